// Round 1
// baseline (796.383 us; speedup 1.0000x reference)
//
#include <hip/hip_runtime.h>

#define MM_BK 32
#define SCAN_CHUNK 2048

// ---------------- edge_index dtype detect + convert ----------------
// If ei is int64 (little-endian, values < 2^31), every odd int32 word of the
// first 128 values is 0. With genuine int32 edge data those words are random
// node indices (P(zero)=1/N each) -> misdetect probability ~(1/N)^128 ~ 0.
__global__ void detect_kernel(const int* __restrict__ ei, int* __restrict__ flag) {
  if (threadIdx.x == 0 && blockIdx.x == 0) {
    int is64 = 1;
    for (int i = 1; i < 256; i += 2)
      if (ei[i] != 0) { is64 = 0; break; }
    *flag = is64;
  }
}

__global__ __launch_bounds__(256) void convert_kernel(const void* __restrict__ ei,
                                                      const int* __restrict__ flag,
                                                      int* __restrict__ src,
                                                      int* __restrict__ dst, int E) {
  int e = blockIdx.x * 256 + threadIdx.x;
  if (e >= E) return;
  if (*flag) {
    const long long* p = (const long long*)ei;
    src[e] = (int)p[e];
    dst[e] = (int)p[E + e];
  } else {
    const int* p = (const int*)ei;
    src[e] = p[e];
    dst[e] = p[E + e];
  }
}

// ---------------- degree histogram ----------------
__global__ __launch_bounds__(256) void hist_kernel(const int* __restrict__ dst,
                                                   int* __restrict__ degi, int E) {
  int e = blockIdx.x * 256 + threadIdx.x;
  if (e < E) atomicAdd(&degi[dst[e]], 1);
}

__global__ __launch_bounds__(256) void dinv_kernel(const int* __restrict__ degi,
                                                   float* __restrict__ dinv, int N) {
  int n = blockIdx.x * 256 + threadIdx.x;
  if (n < N) dinv[n] = rsqrtf((float)degi[n] + 1.0f);
}

// ---------------- exclusive scan (3-kernel, chunked) ----------------
__global__ __launch_bounds__(256) void chunk_reduce_kernel(const int* __restrict__ degi,
                                                           int* __restrict__ partials, int N) {
  __shared__ int s[256];
  int base = blockIdx.x * SCAN_CHUNK;
  int sum = 0;
  for (int j = 0; j < 8; ++j) {
    int i = base + threadIdx.x * 8 + j;
    if (i < N) sum += degi[i];
  }
  s[threadIdx.x] = sum;
  __syncthreads();
  for (int ofs = 128; ofs > 0; ofs >>= 1) {
    if ((int)threadIdx.x < ofs) s[threadIdx.x] += s[threadIdx.x + ofs];
    __syncthreads();
  }
  if (threadIdx.x == 0) partials[blockIdx.x] = s[0];
}

__global__ void scan_partials_kernel(int* __restrict__ partials, int nchunk,
                                     int* __restrict__ rowptr, int N, int E) {
  if (threadIdx.x == 0 && blockIdx.x == 0) {
    int acc = 0;
    for (int c = 0; c < nchunk; ++c) {
      int v = partials[c];
      partials[c] = acc;
      acc += v;
    }
    rowptr[N] = E;
  }
}

__global__ __launch_bounds__(256) void chunk_scan_kernel(const int* __restrict__ degi,
                                                         const int* __restrict__ partials,
                                                         int* __restrict__ rowptr, int N) {
  __shared__ int s[256];
  int base = blockIdx.x * SCAN_CHUNK;
  int t = threadIdx.x;
  int v[8];
  int tsum = 0;
  for (int j = 0; j < 8; ++j) {
    int i = base + t * 8 + j;
    v[j] = (i < N) ? degi[i] : 0;
    tsum += v[j];
  }
  s[t] = tsum;
  __syncthreads();
  for (int ofs = 1; ofs < 256; ofs <<= 1) {
    int add = (t >= ofs) ? s[t - ofs] : 0;
    __syncthreads();
    s[t] += add;
    __syncthreads();
  }
  int run = s[t] - tsum + partials[blockIdx.x];  // exclusive prefix for this thread
  for (int j = 0; j < 8; ++j) {
    int i = base + t * 8 + j;
    if (i < N) rowptr[i] = run;
    run += v[j];
  }
}

// ---------------- counting-sort scatter of edges by dst ----------------
__global__ __launch_bounds__(256) void scatter_kernel(const int* __restrict__ src,
                                                      const int* __restrict__ dst,
                                                      const int* __restrict__ rowptr,
                                                      int* __restrict__ cnt,
                                                      int* __restrict__ esrc, int E) {
  int e = blockIdx.x * 256 + threadIdx.x;
  if (e >= E) return;
  int d = dst[e];
  int slot = rowptr[d] + atomicAdd(&cnt[d], 1);
  esrc[slot] = src[e];
}

// ---------------- pad fcW3 (128x121 -> 128x128) and fcb3 ----------------
__global__ __launch_bounds__(256) void pad_w_kernel(const float* __restrict__ W,
                                                    const float* __restrict__ b,
                                                    float* __restrict__ Wp,
                                                    float* __restrict__ bp) {
  int i = blockIdx.x * 256 + threadIdx.x;
  if (i < 128 * 128) {
    int r = i >> 7, c = i & 127;
    Wp[i] = (c < 121) ? W[r * 121 + c] : 0.f;
  }
  if (i < 128) bp[i] = (i < 121) ? b[i] : 0.f;
}

// ---------------- f32 matmul: Y[N x 128] = X[N x K] @ W[K x 128] ----------------
// block = 256 threads, computes a 64-row x 128-col tile. Each thread: 4 rows x 8 cols.
// Col mapping per thread: {tx*4..tx*4+3} and {64+tx*4..64+tx*4+3} so a wave's 16
// distinct float4 LDS reads cover a contiguous 256B span (2 lanes/bank = free).
template <bool BIAS, bool RELU, bool STORE121>
__global__ __launch_bounds__(256) void mm_kernel(const float* __restrict__ X, int K,
                                                 const float* __restrict__ W,
                                                 const float* __restrict__ bias,
                                                 float* __restrict__ Y, int N) {
  __shared__ float Xs[64][MM_BK + 1];
  __shared__ float Ws[MM_BK][128];
  const int t = threadIdx.x;
  const int tx = t & 15;   // col group
  const int ty = t >> 4;   // row group (0..15), 4 rows each
  const int row0 = blockIdx.x * 64;

  float acc[4][8];
#pragma unroll
  for (int r = 0; r < 4; ++r)
#pragma unroll
    for (int j = 0; j < 8; ++j) acc[r][j] = 0.f;

  const int nkb = (K + MM_BK - 1) / MM_BK;
  for (int kb = 0; kb < nkb; ++kb) {
    const int k0 = kb * MM_BK;
    // stage X tile (64 x 32)
#pragma unroll
    for (int j = 0; j < 8; ++j) {
      int l = t + 256 * j;
      int r = l >> 5, c = l & 31;
      int gr = row0 + r, gc = k0 + c;
      Xs[r][c] = (gr < N && gc < K) ? X[gr * K + gc] : 0.f;
    }
    // stage W tile (32 x 128)
#pragma unroll
    for (int j = 0; j < 16; ++j) {
      int l = t + 256 * j;
      int r = l >> 7, c = l & 127;
      int gk = k0 + r;
      Ws[r][c] = (gk < K) ? W[gk * 128 + c] : 0.f;
    }
    __syncthreads();
#pragma unroll
    for (int kk = 0; kk < MM_BK; ++kk) {
      float4 w0 = *(const float4*)&Ws[kk][tx * 4];
      float4 w1 = *(const float4*)&Ws[kk][64 + tx * 4];
      float xv[4];
#pragma unroll
      for (int r = 0; r < 4; ++r) xv[r] = Xs[ty * 4 + r][kk];
#pragma unroll
      for (int r = 0; r < 4; ++r) {
        acc[r][0] += xv[r] * w0.x;
        acc[r][1] += xv[r] * w0.y;
        acc[r][2] += xv[r] * w0.z;
        acc[r][3] += xv[r] * w0.w;
        acc[r][4] += xv[r] * w1.x;
        acc[r][5] += xv[r] * w1.y;
        acc[r][6] += xv[r] * w1.z;
        acc[r][7] += xv[r] * w1.w;
      }
    }
    __syncthreads();
  }

  // epilogue
#pragma unroll
  for (int r = 0; r < 4; ++r) {
    int row = row0 + ty * 4 + r;
    if (row >= N) continue;
    float v[8];
#pragma unroll
    for (int j = 0; j < 8; ++j) {
      int col = (j < 4) ? (tx * 4 + j) : (64 + tx * 4 + (j - 4));
      float x = acc[r][j];
      if (BIAS) x += bias[col];
      if (RELU) x = fmaxf(x, 0.f);
      v[j] = x;
    }
    if (STORE121) {
#pragma unroll
      for (int j = 0; j < 8; ++j) {
        int col = (j < 4) ? (tx * 4 + j) : (64 + tx * 4 + (j - 4));
        if (col < 121) Y[row * 121 + col] = v[j];
      }
    } else {
      *(float4*)&Y[row * 128 + tx * 4] = make_float4(v[0], v[1], v[2], v[3]);
      *(float4*)&Y[row * 128 + 64 + tx * 4] = make_float4(v[4], v[5], v[6], v[7]);
    }
  }
}

// ---------------- CSR aggregation + self-loop + bias + relu, fused ----------------
// One wave per node: lane holds 2 of 128 features; loop over the node's edge list.
__global__ __launch_bounds__(256) void agg_kernel(const float* __restrict__ Hm,
                                                  const int* __restrict__ rowptr,
                                                  const int* __restrict__ esrc,
                                                  const float* __restrict__ dinv,
                                                  const float* __restrict__ b,
                                                  float* __restrict__ Y, int N) {
  int wave = threadIdx.x >> 6;
  int lane = threadIdx.x & 63;
  int n = blockIdx.x * 4 + wave;
  if (n >= N) return;
  int f = lane * 2;
  float ax = 0.f, ay = 0.f;
  int beg = rowptr[n], end = rowptr[n + 1];
  float dn = dinv[n];
  for (int i = beg; i < end; ++i) {
    int s = esrc[i];
    float nm = dinv[s] * dn;
    float2 h = *(const float2*)&Hm[s * 128 + f];
    ax += h.x * nm;
    ay += h.y * nm;
  }
  float2 hs = *(const float2*)&Hm[n * 128 + f];
  float d2 = dn * dn;
  ax += hs.x * d2 + b[f];
  ay += hs.y * d2 + b[f + 1];
  ax = fmaxf(ax, 0.f);
  ay = fmaxf(ay, 0.f);
  *(float2*)&Y[n * 128 + f] = make_float2(ax, ay);
}

// ---------------- launch ----------------
extern "C" void kernel_launch(void* const* d_in, const int* in_sizes, int n_in,
                              void* d_out, int out_size, void* d_ws, size_t ws_size,
                              hipStream_t stream) {
  const float* x    = (const float*)d_in[0];
  const void*  ei   = d_in[1];
  const float* W1   = (const float*)d_in[3];
  const float* b1   = (const float*)d_in[4];
  const float* W2   = (const float*)d_in[5];
  const float* b2   = (const float*)d_in[6];
  const float* W3   = (const float*)d_in[7];
  const float* b3   = (const float*)d_in[8];
  const float* fcW1 = (const float*)d_in[9];
  const float* fcb1 = (const float*)d_in[10];
  const float* fcW2 = (const float*)d_in[11];
  const float* fcb2 = (const float*)d_in[12];
  const float* fcW3 = (const float*)d_in[13];
  const float* fcb3 = (const float*)d_in[14];

  const int FIN = 50;
  const int N = in_sizes[0] / FIN;
  const int E = in_sizes[1] / 2;
  const int NCHUNK = (N + SCAN_CHUNK - 1) / SCAN_CHUNK;

  // carve workspace
  size_t off = 0;
  auto carve = [&](size_t bytes) {
    void* p = (char*)d_ws + off;
    off += (bytes + 255) & ~(size_t)255;
    return p;
  };
  int*   flag     = (int*)carve(16);
  int*   src32    = (int*)carve((size_t)E * 4);
  int*   dst32    = (int*)carve((size_t)E * 4);
  int*   esrc     = (int*)carve((size_t)E * 4);
  int*   degi     = (int*)carve((size_t)N * 4);  // reused as cnt for scatter
  int*   rowptr   = (int*)carve((size_t)(N + 1) * 4);
  float* dinv     = (float*)carve((size_t)N * 4);
  int*   partials = (int*)carve((size_t)NCHUNK * 4);
  float* Wpad     = (float*)carve(128 * 128 * 4);
  float* bpad     = (float*)carve(128 * 4);
  float* bufA     = (float*)carve((size_t)N * 128 * 4);
  float* bufB     = (float*)carve((size_t)N * 128 * 4);

  const int gE = (E + 255) / 256;
  const int gN = (N + 255) / 256;
  const int gMM = (N + 63) / 64;
  const int gAGG = (N + 3) / 4;

  // --- graph preprocessing ---
  hipMemsetAsync(degi, 0, (size_t)N * 4, stream);
  detect_kernel<<<1, 64, 0, stream>>>((const int*)ei, flag);
  convert_kernel<<<gE, 256, 0, stream>>>(ei, flag, src32, dst32, E);
  hist_kernel<<<gE, 256, 0, stream>>>(dst32, degi, E);
  chunk_reduce_kernel<<<NCHUNK, 256, 0, stream>>>(degi, partials, N);
  scan_partials_kernel<<<1, 64, 0, stream>>>(partials, NCHUNK, rowptr, N, E);
  chunk_scan_kernel<<<NCHUNK, 256, 0, stream>>>(degi, partials, rowptr, N);
  dinv_kernel<<<gN, 256, 0, stream>>>(degi, dinv, N);
  hipMemsetAsync(degi, 0, (size_t)N * 4, stream);  // degi now = cnt
  scatter_kernel<<<gE, 256, 0, stream>>>(src32, dst32, rowptr, degi, esrc, E);
  pad_w_kernel<<<64, 256, 0, stream>>>(fcW3, fcb3, Wpad, bpad);

  // --- conv layer 1: H = x @ W1; A = relu(agg(H) + b1) ---
  mm_kernel<false, false, false><<<gMM, 256, 0, stream>>>(x, FIN, W1, nullptr, bufB, N);
  agg_kernel<<<gAGG, 256, 0, stream>>>(bufB, rowptr, esrc, dinv, b1, bufA, N);
  // --- conv layer 2 ---
  mm_kernel<false, false, false><<<gMM, 256, 0, stream>>>(bufA, 128, W2, nullptr, bufB, N);
  agg_kernel<<<gAGG, 256, 0, stream>>>(bufB, rowptr, esrc, dinv, b2, bufA, N);
  // --- conv layer 3 ---
  mm_kernel<false, false, false><<<gMM, 256, 0, stream>>>(bufA, 128, W3, nullptr, bufB, N);
  agg_kernel<<<gAGG, 256, 0, stream>>>(bufB, rowptr, esrc, dinv, b3, bufA, N);
  // --- FC head ---
  mm_kernel<true, true, false><<<gMM, 256, 0, stream>>>(bufA, 128, fcW1, fcb1, bufB, N);
  mm_kernel<true, true, false><<<gMM, 256, 0, stream>>>(bufB, 128, fcW2, fcb2, bufA, N);
  mm_kernel<true, false, true><<<gMM, 256, 0, stream>>>(bufA, 128, Wpad, bpad, (float*)d_out, N);
}

// Round 2
// 497.978 us; speedup vs baseline: 1.5992x; 1.5992x over previous
//
#include <hip/hip_runtime.h>

#define SCAN_CHUNK 2048

typedef short s16x8 __attribute__((ext_vector_type(8)));
typedef float f32x4 __attribute__((ext_vector_type(4)));

__device__ inline ushort f2b(float f) {
  uint u = __float_as_uint(f);
  return (ushort)((u + 0x7fffu + ((u >> 16) & 1u)) >> 16);
}
__device__ inline float b2f(uint h) { return __uint_as_float(h << 16); }

// ---------------- edge_index dtype detect + convert ----------------
__global__ void detect_kernel(const int* __restrict__ ei, int* __restrict__ flag) {
  if (threadIdx.x == 0 && blockIdx.x == 0) {
    int is64 = 1;
    for (int i = 1; i < 256; i += 2)
      if (ei[i] != 0) { is64 = 0; break; }
    *flag = is64;
  }
}

__global__ __launch_bounds__(256) void convert_kernel(const void* __restrict__ ei,
                                                      const int* __restrict__ flag,
                                                      int* __restrict__ src,
                                                      int* __restrict__ dst, int E) {
  int e = blockIdx.x * 256 + threadIdx.x;
  if (e >= E) return;
  if (*flag) {
    const long long* p = (const long long*)ei;
    src[e] = (int)p[e];
    dst[e] = (int)p[E + e];
  } else {
    const int* p = (const int*)ei;
    src[e] = p[e];
    dst[e] = p[E + e];
  }
}

// ---------------- degree histogram ----------------
__global__ __launch_bounds__(256) void hist_kernel(const int* __restrict__ dst,
                                                   int* __restrict__ degi, int E) {
  int e = blockIdx.x * 256 + threadIdx.x;
  if (e < E) atomicAdd(&degi[dst[e]], 1);
}

__global__ __launch_bounds__(256) void dinv_kernel(const int* __restrict__ degi,
                                                   float* __restrict__ dinv, int N) {
  int n = blockIdx.x * 256 + threadIdx.x;
  if (n < N) dinv[n] = rsqrtf((float)degi[n] + 1.0f);
}

// ---------------- exclusive scan (3-kernel, chunked) ----------------
__global__ __launch_bounds__(256) void chunk_reduce_kernel(const int* __restrict__ degi,
                                                           int* __restrict__ partials, int N) {
  __shared__ int s[256];
  int base = blockIdx.x * SCAN_CHUNK;
  int sum = 0;
  for (int j = 0; j < 8; ++j) {
    int i = base + threadIdx.x * 8 + j;
    if (i < N) sum += degi[i];
  }
  s[threadIdx.x] = sum;
  __syncthreads();
  for (int ofs = 128; ofs > 0; ofs >>= 1) {
    if ((int)threadIdx.x < ofs) s[threadIdx.x] += s[threadIdx.x + ofs];
    __syncthreads();
  }
  if (threadIdx.x == 0) partials[blockIdx.x] = s[0];
}

__global__ void scan_partials_kernel(int* __restrict__ partials, int nchunk,
                                     int* __restrict__ rowptr, int N, int E) {
  if (threadIdx.x == 0 && blockIdx.x == 0) {
    int acc = 0;
    for (int c = 0; c < nchunk; ++c) {
      int v = partials[c];
      partials[c] = acc;
      acc += v;
    }
    rowptr[N] = E;
  }
}

__global__ __launch_bounds__(256) void chunk_scan_kernel(const int* __restrict__ degi,
                                                         const int* __restrict__ partials,
                                                         int* __restrict__ rowptr, int N) {
  __shared__ int s[256];
  int base = blockIdx.x * SCAN_CHUNK;
  int t = threadIdx.x;
  int v[8];
  int tsum = 0;
  for (int j = 0; j < 8; ++j) {
    int i = base + t * 8 + j;
    v[j] = (i < N) ? degi[i] : 0;
    tsum += v[j];
  }
  s[t] = tsum;
  __syncthreads();
  for (int ofs = 1; ofs < 256; ofs <<= 1) {
    int add = (t >= ofs) ? s[t - ofs] : 0;
    __syncthreads();
    s[t] += add;
    __syncthreads();
  }
  int run = s[t] - tsum + partials[blockIdx.x];
  for (int j = 0; j < 8; ++j) {
    int i = base + t * 8 + j;
    if (i < N) rowptr[i] = run;
    run += v[j];
  }
}

// ---------------- counting-sort scatter of edges by dst ----------------
__global__ __launch_bounds__(256) void scatter_kernel(const int* __restrict__ src,
                                                      const int* __restrict__ dst,
                                                      const int* __restrict__ rowptr,
                                                      int* __restrict__ cnt,
                                                      int* __restrict__ esrc, int E) {
  int e = blockIdx.x * 256 + threadIdx.x;
  if (e >= E) return;
  int d = dst[e];
  int slot = rowptr[d] + atomicAdd(&cnt[d], 1);
  esrc[slot] = src[e];
}

// ---------------- weight prep: W[K x ncol] f32 -> Wt[2][128][Kp] bf16 (hi/lo, transposed, padded) ----------------
__global__ __launch_bounds__(256) void prep_w(const float* __restrict__ W, int K, int Kp,
                                              int ncol, ushort* __restrict__ Wt) {
  int i = blockIdx.x * 256 + threadIdx.x;
  if (i >= 128 * Kp) return;
  int c = i / Kp, k = i - c * Kp;
  float w = (k < K && c < ncol) ? W[(size_t)k * ncol + c] : 0.f;
  ushort hi = f2b(w);
  float rem = w - b2f(hi);
  ushort lo = f2b(rem);
  Wt[(size_t)c * Kp + k] = hi;
  Wt[(size_t)128 * Kp + (size_t)c * Kp + k] = lo;
}

// ---------------- x f32 [N x 50] -> bf16 [N x 64] zero-padded ----------------
__global__ __launch_bounds__(256) void conv_x_kernel(const float* __restrict__ x,
                                                     ushort* __restrict__ xb, int N) {
  int i = blockIdx.x * 256 + threadIdx.x;
  if (i >= N * 64) return;
  int n = i >> 6, k = i & 63;
  xb[i] = (k < 50) ? f2b(x[(size_t)n * 50 + k]) : (ushort)0;
}

// ---------------- MFMA matmul: Y[N x 128] = X[N x K]bf16 @ (Whi+Wlo)[K x 128] ----------------
// One wave per 32 rows. A-frags from global X; B-frags from global Wt (L2-resident).
// mfma_f32_16x16x32_bf16 layouts: A: row=lane&15, k=(lane>>4)*8+j (16B contiguous);
// B: col=lane&15, k=(lane>>4)*8+j (16B contiguous in W^T); D: col=lane&15, row=(lane>>4)*4+reg.
template <int KSTEPS, bool BIAS, bool RELU, bool FINAL>
__global__ __launch_bounds__(256) void mm_mfma(const ushort* __restrict__ X,
                                               const ushort* __restrict__ Wt,
                                               const float* __restrict__ bias,
                                               ushort* __restrict__ Yb,
                                               float* __restrict__ Yf, int N) {
  constexpr int K = KSTEPS * 32;
  const int lane = threadIdx.x & 63;
  const int wid = (blockIdx.x * 256 + threadIdx.x) >> 6;
  const long r0 = (long)wid * 32;
  if (r0 >= N) return;
  const bool v1 = (r0 + 16) < N;  // second 16-row frag valid (N % 16 == 0)
  const int am = lane & 15;
  const int ag = lane >> 4;
  const ushort* __restrict__ wbase = Wt + (size_t)am * K + ag * 8;
  const ushort* __restrict__ x0 = X + (size_t)(r0 + am) * K + ag * 8;

  f32x4 acc[2][8] = {};
  for (int ks = 0; ks < KSTEPS; ++ks) {
    s16x8 a0 = *(const s16x8*)(x0 + ks * 32);
    s16x8 a1 = {};
    if (v1) a1 = *(const s16x8*)(x0 + (size_t)16 * K + ks * 32);
#pragma unroll
    for (int f = 0; f < 8; ++f) {
      const ushort* wp = wbase + (size_t)f * 16 * K + ks * 32;
      s16x8 bh = *(const s16x8*)(wp);
      s16x8 bl = *(const s16x8*)(wp + (size_t)128 * K);
      acc[0][f] = __builtin_amdgcn_mfma_f32_16x16x32_bf16(a0, bh, acc[0][f], 0, 0, 0);
      acc[0][f] = __builtin_amdgcn_mfma_f32_16x16x32_bf16(a0, bl, acc[0][f], 0, 0, 0);
      if (v1) {
        acc[1][f] = __builtin_amdgcn_mfma_f32_16x16x32_bf16(a1, bh, acc[1][f], 0, 0, 0);
        acc[1][f] = __builtin_amdgcn_mfma_f32_16x16x32_bf16(a1, bl, acc[1][f], 0, 0, 0);
      }
    }
  }

  const int dr = (lane >> 4) * 4;
  const int dc = lane & 15;
#pragma unroll
  for (int m = 0; m < 2; ++m) {
    if (m == 1 && !v1) break;
#pragma unroll
    for (int f = 0; f < 8; ++f) {
      int col = f * 16 + dc;
      float bv = 0.f;
      if (BIAS) {
        if (!FINAL || col < 121) bv = bias[col];
      }
#pragma unroll
      for (int r = 0; r < 4; ++r) {
        long row = r0 + m * 16 + dr + r;
        float v = acc[m][f][r] + bv;
        if (RELU) v = fmaxf(v, 0.f);
        if (FINAL) {
          if (col < 121) Yf[row * 121 + col] = v;
        } else {
          Yb[row * 128 + col] = f2b(v);
        }
      }
    }
  }
}

// ---------------- CSR aggregation + self-loop + bias + relu, fused (bf16 in/out) ----------------
__global__ __launch_bounds__(256) void agg_kernel(const ushort* __restrict__ Hm,
                                                  const int* __restrict__ rowptr,
                                                  const int* __restrict__ esrc,
                                                  const float* __restrict__ dinv,
                                                  const float* __restrict__ b,
                                                  ushort* __restrict__ Y, int N) {
  int wave = threadIdx.x >> 6;
  int lane = threadIdx.x & 63;
  int n = blockIdx.x * 4 + wave;
  if (n >= N) return;
  int f = lane * 2;
  float ax = 0.f, ay = 0.f;
  int beg = rowptr[n], end = rowptr[n + 1];
  float dn = dinv[n];
  for (int i = beg; i < end; ++i) {
    int s = esrc[i];
    float nm = dinv[s] * dn;
    uint v = *(const uint*)&Hm[(size_t)s * 128 + f];
    ax += b2f(v & 0xffffu) * nm;
    ay += b2f(v >> 16) * nm;
  }
  uint sv = *(const uint*)&Hm[(size_t)n * 128 + f];
  float d2 = dn * dn;
  ax += b2f(sv & 0xffffu) * d2 + b[f];
  ay += b2f(sv >> 16) * d2 + b[f + 1];
  ax = fmaxf(ax, 0.f);
  ay = fmaxf(ay, 0.f);
  uint out = (uint)f2b(ax) | ((uint)f2b(ay) << 16);
  *(uint*)&Y[(size_t)n * 128 + f] = out;
}

// ---------------- launch ----------------
extern "C" void kernel_launch(void* const* d_in, const int* in_sizes, int n_in,
                              void* d_out, int out_size, void* d_ws, size_t ws_size,
                              hipStream_t stream) {
  const float* x    = (const float*)d_in[0];
  const void*  ei   = d_in[1];
  const float* W1   = (const float*)d_in[3];
  const float* b1   = (const float*)d_in[4];
  const float* W2   = (const float*)d_in[5];
  const float* b2   = (const float*)d_in[6];
  const float* W3   = (const float*)d_in[7];
  const float* b3   = (const float*)d_in[8];
  const float* fcW1 = (const float*)d_in[9];
  const float* fcb1 = (const float*)d_in[10];
  const float* fcW2 = (const float*)d_in[11];
  const float* fcb2 = (const float*)d_in[12];
  const float* fcW3 = (const float*)d_in[13];
  const float* fcb3 = (const float*)d_in[14];

  const int FIN = 50;
  const int N = in_sizes[0] / FIN;
  const int E = in_sizes[1] / 2;
  const int NCHUNK = (N + SCAN_CHUNK - 1) / SCAN_CHUNK;

  size_t off = 0;
  auto carve = [&](size_t bytes) {
    void* p = (char*)d_ws + off;
    off += (bytes + 255) & ~(size_t)255;
    return p;
  };
  int*    flag     = (int*)carve(16);
  int*    src32    = (int*)carve((size_t)E * 4);
  int*    dst32    = (int*)carve((size_t)E * 4);
  int*    esrc     = (int*)carve((size_t)E * 4);
  int*    degi     = (int*)carve((size_t)N * 4);  // reused as cnt for scatter
  int*    rowptr   = (int*)carve((size_t)(N + 1) * 4);
  float*  dinv     = (float*)carve((size_t)N * 4);
  int*    partials = (int*)carve((size_t)NCHUNK * 4);
  ushort* W1t      = (ushort*)carve((size_t)2 * 128 * 64 * 2);
  ushort* W2t      = (ushort*)carve((size_t)2 * 128 * 128 * 2);
  ushort* W3t      = (ushort*)carve((size_t)2 * 128 * 128 * 2);
  ushort* F1t      = (ushort*)carve((size_t)2 * 128 * 128 * 2);
  ushort* F2t      = (ushort*)carve((size_t)2 * 128 * 128 * 2);
  ushort* F3t      = (ushort*)carve((size_t)2 * 128 * 128 * 2);
  ushort* xb       = (ushort*)carve((size_t)N * 64 * 2);
  ushort* bufA     = (ushort*)carve((size_t)N * 128 * 2);
  ushort* bufB     = (ushort*)carve((size_t)N * 128 * 2);

  const int gE = (E + 255) / 256;
  const int gN = (N + 255) / 256;
  const int gMM = (N + 127) / 128;     // 4 waves/block, 32 rows/wave
  const int gAGG = (N + 3) / 4;

  // --- graph preprocessing ---
  hipMemsetAsync(degi, 0, (size_t)N * 4, stream);
  detect_kernel<<<1, 64, 0, stream>>>((const int*)ei, flag);
  convert_kernel<<<gE, 256, 0, stream>>>(ei, flag, src32, dst32, E);
  hist_kernel<<<gE, 256, 0, stream>>>(dst32, degi, E);
  chunk_reduce_kernel<<<NCHUNK, 256, 0, stream>>>(degi, partials, N);
  scan_partials_kernel<<<1, 64, 0, stream>>>(partials, NCHUNK, rowptr, N, E);
  chunk_scan_kernel<<<NCHUNK, 256, 0, stream>>>(degi, partials, rowptr, N);
  dinv_kernel<<<gN, 256, 0, stream>>>(degi, dinv, N);
  hipMemsetAsync(degi, 0, (size_t)N * 4, stream);
  scatter_kernel<<<gE, 256, 0, stream>>>(src32, dst32, rowptr, degi, esrc, E);

  // --- weight prep + input conversion ---
  prep_w<<<(128 * 64 + 255) / 256, 256, 0, stream>>>(W1, FIN, 64, 128, W1t);
  prep_w<<<(128 * 128 + 255) / 256, 256, 0, stream>>>(W2, 128, 128, 128, W2t);
  prep_w<<<(128 * 128 + 255) / 256, 256, 0, stream>>>(W3, 128, 128, 128, W3t);
  prep_w<<<(128 * 128 + 255) / 256, 256, 0, stream>>>(fcW1, 128, 128, 128, F1t);
  prep_w<<<(128 * 128 + 255) / 256, 256, 0, stream>>>(fcW2, 128, 128, 128, F2t);
  prep_w<<<(128 * 128 + 255) / 256, 256, 0, stream>>>(fcW3, 128, 128, 121, F3t);
  conv_x_kernel<<<(N * 64 + 255) / 256, 256, 0, stream>>>(x, xb, N);

  // --- conv layer 1 ---
  mm_mfma<2, false, false, false><<<gMM, 256, 0, stream>>>(xb, W1t, nullptr, bufB, nullptr, N);
  agg_kernel<<<gAGG, 256, 0, stream>>>(bufB, rowptr, esrc, dinv, b1, bufA, N);
  // --- conv layer 2 ---
  mm_mfma<4, false, false, false><<<gMM, 256, 0, stream>>>(bufA, W2t, nullptr, bufB, nullptr, N);
  agg_kernel<<<gAGG, 256, 0, stream>>>(bufB, rowptr, esrc, dinv, b2, bufA, N);
  // --- conv layer 3 ---
  mm_mfma<4, false, false, false><<<gMM, 256, 0, stream>>>(bufA, W3t, nullptr, bufB, nullptr, N);
  agg_kernel<<<gAGG, 256, 0, stream>>>(bufB, rowptr, esrc, dinv, b3, bufA, N);
  // --- FC head ---
  mm_mfma<4, true, true, false><<<gMM, 256, 0, stream>>>(bufA, F1t, fcb1, bufB, nullptr, N);
  mm_mfma<4, true, true, false><<<gMM, 256, 0, stream>>>(bufB, F2t, fcb2, bufA, nullptr, N);
  mm_mfma<4, true, false, true><<<gMM, 256, 0, stream>>>(bufA, F3t, fcb3, nullptr, (float*)d_out, N);
}

// Round 3
// 356.026 us; speedup vs baseline: 2.2369x; 1.3987x over previous
//
#include <hip/hip_runtime.h>

#define SCAN_CHUNK 2048

typedef short s16x8 __attribute__((ext_vector_type(8)));
typedef float f32x4 __attribute__((ext_vector_type(4)));

__device__ inline ushort f2b(float f) {
  uint u = __float_as_uint(f);
  return (ushort)((u + 0x7fffu + ((u >> 16) & 1u)) >> 16);
}
__device__ inline float b2f(uint h) { return __uint_as_float(h << 16); }

// ---------------- edge_index dtype detect + convert ----------------
__global__ void detect_kernel(const int* __restrict__ ei, int* __restrict__ flag) {
  if (threadIdx.x == 0 && blockIdx.x == 0) {
    int is64 = 1;
    for (int i = 1; i < 256; i += 2)
      if (ei[i] != 0) { is64 = 0; break; }
    *flag = is64;
  }
}

__global__ __launch_bounds__(256) void convert_kernel(const void* __restrict__ ei,
                                                      const int* __restrict__ flag,
                                                      int* __restrict__ src,
                                                      int* __restrict__ dst, int E) {
  int e = blockIdx.x * 256 + threadIdx.x;
  if (e >= E) return;
  if (*flag) {
    const long long* p = (const long long*)ei;
    src[e] = (int)p[e];
    dst[e] = (int)p[E + e];
  } else {
    const int* p = (const int*)ei;
    src[e] = p[e];
    dst[e] = p[E + e];
  }
}

// ---------------- degree histogram ----------------
__global__ __launch_bounds__(256) void hist_kernel(const int* __restrict__ dst,
                                                   int* __restrict__ degi, int E) {
  int e = blockIdx.x * 256 + threadIdx.x;
  if (e < E) atomicAdd(&degi[dst[e]], 1);
}

__global__ __launch_bounds__(256) void dinv_kernel(const int* __restrict__ degi,
                                                   float* __restrict__ dinv, int N) {
  int n = blockIdx.x * 256 + threadIdx.x;
  if (n < N) dinv[n] = rsqrtf((float)degi[n] + 1.0f);
}

// ---------------- exclusive scan (3-kernel, chunked) ----------------
__global__ __launch_bounds__(256) void chunk_reduce_kernel(const int* __restrict__ degi,
                                                           int* __restrict__ partials, int N) {
  __shared__ int s[256];
  int base = blockIdx.x * SCAN_CHUNK;
  int sum = 0;
  for (int j = 0; j < 8; ++j) {
    int i = base + threadIdx.x * 8 + j;
    if (i < N) sum += degi[i];
  }
  s[threadIdx.x] = sum;
  __syncthreads();
  for (int ofs = 128; ofs > 0; ofs >>= 1) {
    if ((int)threadIdx.x < ofs) s[threadIdx.x] += s[threadIdx.x + ofs];
    __syncthreads();
  }
  if (threadIdx.x == 0) partials[blockIdx.x] = s[0];
}

__global__ void scan_partials_kernel(int* __restrict__ partials, int nchunk,
                                     int* __restrict__ rowptr, int N, int E) {
  if (threadIdx.x == 0 && blockIdx.x == 0) {
    int acc = 0;
    for (int c = 0; c < nchunk; ++c) {
      int v = partials[c];
      partials[c] = acc;
      acc += v;
    }
    rowptr[N] = E;
  }
}

__global__ __launch_bounds__(256) void chunk_scan_kernel(const int* __restrict__ degi,
                                                         const int* __restrict__ partials,
                                                         int* __restrict__ rowptr, int N) {
  __shared__ int s[256];
  int base = blockIdx.x * SCAN_CHUNK;
  int t = threadIdx.x;
  int v[8];
  int tsum = 0;
  for (int j = 0; j < 8; ++j) {
    int i = base + t * 8 + j;
    v[j] = (i < N) ? degi[i] : 0;
    tsum += v[j];
  }
  s[t] = tsum;
  __syncthreads();
  for (int ofs = 1; ofs < 256; ofs <<= 1) {
    int add = (t >= ofs) ? s[t - ofs] : 0;
    __syncthreads();
    s[t] += add;
    __syncthreads();
  }
  int run = s[t] - tsum + partials[blockIdx.x];
  for (int j = 0; j < 8; ++j) {
    int i = base + t * 8 + j;
    if (i < N) rowptr[i] = run;
    run += v[j];
  }
}

// ---------------- counting-sort scatter: edge -> {src, norm} record ----------------
__global__ __launch_bounds__(256) void scatter_kernel(const int* __restrict__ src,
                                                      const int* __restrict__ dst,
                                                      const int* __restrict__ rowptr,
                                                      const float* __restrict__ dinv,
                                                      int* __restrict__ cnt,
                                                      int2* __restrict__ epack, int E) {
  int e = blockIdx.x * 256 + threadIdx.x;
  if (e >= E) return;
  int d = dst[e];
  int s = src[e];
  int slot = rowptr[d] + atomicAdd(&cnt[d], 1);
  float nm = dinv[s] * dinv[d];
  epack[slot] = make_int2(s, __float_as_int(nm));
}

// ---------------- weight prep: W[K x ncol] f32 -> Wt[2][128][Kp] bf16 (hi/lo, transposed, padded) ----------------
__global__ __launch_bounds__(256) void prep_w(const float* __restrict__ W, int K, int Kp,
                                              int ncol, ushort* __restrict__ Wt) {
  int i = blockIdx.x * 256 + threadIdx.x;
  if (i >= 128 * Kp) return;
  int c = i / Kp, k = i - c * Kp;
  float w = (k < K && c < ncol) ? W[(size_t)k * ncol + c] : 0.f;
  ushort hi = f2b(w);
  float rem = w - b2f(hi);
  ushort lo = f2b(rem);
  Wt[(size_t)c * Kp + k] = hi;
  Wt[(size_t)128 * Kp + (size_t)c * Kp + k] = lo;
}

// ---------------- x f32 [N x 50] -> bf16 [N x 64] zero-padded ----------------
__global__ __launch_bounds__(256) void conv_x_kernel(const float* __restrict__ x,
                                                     ushort* __restrict__ xb, int N) {
  int i = blockIdx.x * 256 + threadIdx.x;
  if (i >= N * 64) return;
  int n = i >> 6, k = i & 63;
  xb[i] = (k < 50) ? f2b(x[(size_t)n * 50 + k]) : (ushort)0;
}

// ---------------- MFMA matmul: Y[N x 128] = X[N x K]bf16 @ (Whi+Wlo)[K x 128] ----------------
template <int KSTEPS, bool BIAS, bool RELU, bool FINAL>
__global__ __launch_bounds__(256) void mm_mfma(const ushort* __restrict__ X,
                                               const ushort* __restrict__ Wt,
                                               const float* __restrict__ bias,
                                               ushort* __restrict__ Yb,
                                               float* __restrict__ Yf, int N) {
  constexpr int K = KSTEPS * 32;
  const int lane = threadIdx.x & 63;
  const int wid = (blockIdx.x * 256 + threadIdx.x) >> 6;
  const long r0 = (long)wid * 32;
  if (r0 >= N) return;
  const bool v1 = (r0 + 16) < N;
  const int am = lane & 15;
  const int ag = lane >> 4;
  const ushort* __restrict__ wbase = Wt + (size_t)am * K + ag * 8;
  const ushort* __restrict__ x0 = X + (size_t)(r0 + am) * K + ag * 8;

  f32x4 acc[2][8] = {};
  for (int ks = 0; ks < KSTEPS; ++ks) {
    s16x8 a0 = *(const s16x8*)(x0 + ks * 32);
    s16x8 a1 = {};
    if (v1) a1 = *(const s16x8*)(x0 + (size_t)16 * K + ks * 32);
#pragma unroll
    for (int f = 0; f < 8; ++f) {
      const ushort* wp = wbase + (size_t)f * 16 * K + ks * 32;
      s16x8 bh = *(const s16x8*)(wp);
      s16x8 bl = *(const s16x8*)(wp + (size_t)128 * K);
      acc[0][f] = __builtin_amdgcn_mfma_f32_16x16x32_bf16(a0, bh, acc[0][f], 0, 0, 0);
      acc[0][f] = __builtin_amdgcn_mfma_f32_16x16x32_bf16(a0, bl, acc[0][f], 0, 0, 0);
      if (v1) {
        acc[1][f] = __builtin_amdgcn_mfma_f32_16x16x32_bf16(a1, bh, acc[1][f], 0, 0, 0);
        acc[1][f] = __builtin_amdgcn_mfma_f32_16x16x32_bf16(a1, bl, acc[1][f], 0, 0, 0);
      }
    }
  }

  const int dr = (lane >> 4) * 4;
  const int dc = lane & 15;
#pragma unroll
  for (int m = 0; m < 2; ++m) {
    if (m == 1 && !v1) break;
#pragma unroll
    for (int f = 0; f < 8; ++f) {
      int col = f * 16 + dc;
      float bv = 0.f;
      if (BIAS) {
        if (!FINAL || col < 121) bv = bias[col];
      }
#pragma unroll
      for (int r = 0; r < 4; ++r) {
        long row = r0 + m * 16 + dr + r;
        float v = acc[m][f][r] + bv;
        if (RELU) v = fmaxf(v, 0.f);
        if (FINAL) {
          if (col < 121) Yf[row * 121 + col] = v;
        } else {
          Yb[row * 128 + col] = f2b(v);
        }
      }
    }
  }
}

// ---------------- CSR aggregation, 8-deep software-pipelined gather ----------------
// One wave per node, lane holds 2 of 128 features. Edge records {src, norm} are
// precomputed; per batch we load 8 records then issue 8 INDEPENDENT row gathers
// (8-way memory-level parallelism), then accumulate.
__global__ __launch_bounds__(256) void agg_kernel(const ushort* __restrict__ Hm,
                                                  const int* __restrict__ rowptr,
                                                  const int2* __restrict__ epack,
                                                  const float* __restrict__ dinv,
                                                  const float* __restrict__ b,
                                                  ushort* __restrict__ Y, int N) {
  int wave = threadIdx.x >> 6;
  int lane = threadIdx.x & 63;
  int n = blockIdx.x * 4 + wave;
  if (n >= N) return;
  int f = lane * 2;
  float ax = 0.f, ay = 0.f;
  int beg = rowptr[n], end = rowptr[n + 1];
  int i = beg;

  while (i + 8 <= end) {
    int2 e0 = epack[i + 0], e1 = epack[i + 1], e2 = epack[i + 2], e3 = epack[i + 3];
    int2 e4 = epack[i + 4], e5 = epack[i + 5], e6 = epack[i + 6], e7 = epack[i + 7];
    uint v0 = *(const uint*)&Hm[(size_t)e0.x * 128 + f];
    uint v1 = *(const uint*)&Hm[(size_t)e1.x * 128 + f];
    uint v2 = *(const uint*)&Hm[(size_t)e2.x * 128 + f];
    uint v3 = *(const uint*)&Hm[(size_t)e3.x * 128 + f];
    uint v4 = *(const uint*)&Hm[(size_t)e4.x * 128 + f];
    uint v5 = *(const uint*)&Hm[(size_t)e5.x * 128 + f];
    uint v6 = *(const uint*)&Hm[(size_t)e6.x * 128 + f];
    uint v7 = *(const uint*)&Hm[(size_t)e7.x * 128 + f];
    float n0 = __int_as_float(e0.y), n1 = __int_as_float(e1.y);
    float n2 = __int_as_float(e2.y), n3 = __int_as_float(e3.y);
    float n4 = __int_as_float(e4.y), n5 = __int_as_float(e5.y);
    float n6 = __int_as_float(e6.y), n7 = __int_as_float(e7.y);
    ax += b2f(v0 & 0xffffu) * n0; ay += b2f(v0 >> 16) * n0;
    ax += b2f(v1 & 0xffffu) * n1; ay += b2f(v1 >> 16) * n1;
    ax += b2f(v2 & 0xffffu) * n2; ay += b2f(v2 >> 16) * n2;
    ax += b2f(v3 & 0xffffu) * n3; ay += b2f(v3 >> 16) * n3;
    ax += b2f(v4 & 0xffffu) * n4; ay += b2f(v4 >> 16) * n4;
    ax += b2f(v5 & 0xffffu) * n5; ay += b2f(v5 >> 16) * n5;
    ax += b2f(v6 & 0xffffu) * n6; ay += b2f(v6 >> 16) * n6;
    ax += b2f(v7 & 0xffffu) * n7; ay += b2f(v7 >> 16) * n7;
    i += 8;
  }
  if (i + 4 <= end) {
    int2 e0 = epack[i + 0], e1 = epack[i + 1], e2 = epack[i + 2], e3 = epack[i + 3];
    uint v0 = *(const uint*)&Hm[(size_t)e0.x * 128 + f];
    uint v1 = *(const uint*)&Hm[(size_t)e1.x * 128 + f];
    uint v2 = *(const uint*)&Hm[(size_t)e2.x * 128 + f];
    uint v3 = *(const uint*)&Hm[(size_t)e3.x * 128 + f];
    float n0 = __int_as_float(e0.y), n1 = __int_as_float(e1.y);
    float n2 = __int_as_float(e2.y), n3 = __int_as_float(e3.y);
    ax += b2f(v0 & 0xffffu) * n0; ay += b2f(v0 >> 16) * n0;
    ax += b2f(v1 & 0xffffu) * n1; ay += b2f(v1 >> 16) * n1;
    ax += b2f(v2 & 0xffffu) * n2; ay += b2f(v2 >> 16) * n2;
    ax += b2f(v3 & 0xffffu) * n3; ay += b2f(v3 >> 16) * n3;
    i += 4;
  }
  for (; i < end; ++i) {
    int2 e = epack[i];
    float nm = __int_as_float(e.y);
    uint v = *(const uint*)&Hm[(size_t)e.x * 128 + f];
    ax += b2f(v & 0xffffu) * nm;
    ay += b2f(v >> 16) * nm;
  }

  uint sv = *(const uint*)&Hm[(size_t)n * 128 + f];
  float dn = dinv[n];
  float d2 = dn * dn;
  ax += b2f(sv & 0xffffu) * d2 + b[f];
  ay += b2f(sv >> 16) * d2 + b[f + 1];
  ax = fmaxf(ax, 0.f);
  ay = fmaxf(ay, 0.f);
  uint out = (uint)f2b(ax) | ((uint)f2b(ay) << 16);
  *(uint*)&Y[(size_t)n * 128 + f] = out;
}

// ---------------- launch ----------------
extern "C" void kernel_launch(void* const* d_in, const int* in_sizes, int n_in,
                              void* d_out, int out_size, void* d_ws, size_t ws_size,
                              hipStream_t stream) {
  const float* x    = (const float*)d_in[0];
  const void*  ei   = d_in[1];
  const float* W1   = (const float*)d_in[3];
  const float* b1   = (const float*)d_in[4];
  const float* W2   = (const float*)d_in[5];
  const float* b2   = (const float*)d_in[6];
  const float* W3   = (const float*)d_in[7];
  const float* b3   = (const float*)d_in[8];
  const float* fcW1 = (const float*)d_in[9];
  const float* fcb1 = (const float*)d_in[10];
  const float* fcW2 = (const float*)d_in[11];
  const float* fcb2 = (const float*)d_in[12];
  const float* fcW3 = (const float*)d_in[13];
  const float* fcb3 = (const float*)d_in[14];

  const int FIN = 50;
  const int N = in_sizes[0] / FIN;
  const int E = in_sizes[1] / 2;
  const int NCHUNK = (N + SCAN_CHUNK - 1) / SCAN_CHUNK;

  size_t off = 0;
  auto carve = [&](size_t bytes) {
    void* p = (char*)d_ws + off;
    off += (bytes + 255) & ~(size_t)255;
    return p;
  };
  int*    flag     = (int*)carve(16);
  int*    src32    = (int*)carve((size_t)E * 4);
  int*    dst32    = (int*)carve((size_t)E * 4);
  int2*   epack    = (int2*)carve((size_t)E * 8);
  int*    degi     = (int*)carve((size_t)N * 4);  // reused as cnt for scatter
  int*    rowptr   = (int*)carve((size_t)(N + 1) * 4);
  float*  dinv     = (float*)carve((size_t)N * 4);
  int*    partials = (int*)carve((size_t)NCHUNK * 4);
  ushort* W1t      = (ushort*)carve((size_t)2 * 128 * 64 * 2);
  ushort* W2t      = (ushort*)carve((size_t)2 * 128 * 128 * 2);
  ushort* W3t      = (ushort*)carve((size_t)2 * 128 * 128 * 2);
  ushort* F1t      = (ushort*)carve((size_t)2 * 128 * 128 * 2);
  ushort* F2t      = (ushort*)carve((size_t)2 * 128 * 128 * 2);
  ushort* F3t      = (ushort*)carve((size_t)2 * 128 * 128 * 2);
  ushort* xb       = (ushort*)carve((size_t)N * 64 * 2);
  ushort* bufA     = (ushort*)carve((size_t)N * 128 * 2);
  ushort* bufB     = (ushort*)carve((size_t)N * 128 * 2);

  const int gE = (E + 255) / 256;
  const int gN = (N + 255) / 256;
  const int gMM = (N + 127) / 128;
  const int gAGG = (N + 3) / 4;

  // --- graph preprocessing ---
  hipMemsetAsync(degi, 0, (size_t)N * 4, stream);
  detect_kernel<<<1, 64, 0, stream>>>((const int*)ei, flag);
  convert_kernel<<<gE, 256, 0, stream>>>(ei, flag, src32, dst32, E);
  hist_kernel<<<gE, 256, 0, stream>>>(dst32, degi, E);
  chunk_reduce_kernel<<<NCHUNK, 256, 0, stream>>>(degi, partials, N);
  scan_partials_kernel<<<1, 64, 0, stream>>>(partials, NCHUNK, rowptr, N, E);
  chunk_scan_kernel<<<NCHUNK, 256, 0, stream>>>(degi, partials, rowptr, N);
  dinv_kernel<<<gN, 256, 0, stream>>>(degi, dinv, N);
  hipMemsetAsync(degi, 0, (size_t)N * 4, stream);
  scatter_kernel<<<gE, 256, 0, stream>>>(src32, dst32, rowptr, dinv, degi, epack, E);

  // --- weight prep + input conversion ---
  prep_w<<<(128 * 64 + 255) / 256, 256, 0, stream>>>(W1, FIN, 64, 128, W1t);
  prep_w<<<(128 * 128 + 255) / 256, 256, 0, stream>>>(W2, 128, 128, 128, W2t);
  prep_w<<<(128 * 128 + 255) / 256, 256, 0, stream>>>(W3, 128, 128, 128, W3t);
  prep_w<<<(128 * 128 + 255) / 256, 256, 0, stream>>>(fcW1, 128, 128, 128, F1t);
  prep_w<<<(128 * 128 + 255) / 256, 256, 0, stream>>>(fcW2, 128, 128, 128, F2t);
  prep_w<<<(128 * 128 + 255) / 256, 256, 0, stream>>>(fcW3, 128, 128, 121, F3t);
  conv_x_kernel<<<(N * 64 + 255) / 256, 256, 0, stream>>>(x, xb, N);

  // --- conv layer 1 ---
  mm_mfma<2, false, false, false><<<gMM, 256, 0, stream>>>(xb, W1t, nullptr, bufB, nullptr, N);
  agg_kernel<<<gAGG, 256, 0, stream>>>(bufB, rowptr, epack, dinv, b1, bufA, N);
  // --- conv layer 2 ---
  mm_mfma<4, false, false, false><<<gMM, 256, 0, stream>>>(bufA, W2t, nullptr, bufB, nullptr, N);
  agg_kernel<<<gAGG, 256, 0, stream>>>(bufB, rowptr, epack, dinv, b2, bufA, N);
  // --- conv layer 3 ---
  mm_mfma<4, false, false, false><<<gMM, 256, 0, stream>>>(bufA, W3t, nullptr, bufB, nullptr, N);
  agg_kernel<<<gAGG, 256, 0, stream>>>(bufB, rowptr, epack, dinv, b3, bufA, N);
  // --- FC head ---
  mm_mfma<4, true, true, false><<<gMM, 256, 0, stream>>>(bufA, F1t, fcb1, bufB, nullptr, N);
  mm_mfma<4, true, true, false><<<gMM, 256, 0, stream>>>(bufB, F2t, fcb2, bufA, nullptr, N);
  mm_mfma<4, true, false, true><<<gMM, 256, 0, stream>>>(bufA, F3t, fcb3, nullptr, (float*)d_out, N);
}

// Round 4
// 321.453 us; speedup vs baseline: 2.4774x; 1.1076x over previous
//
#include <hip/hip_runtime.h>

#define SCAN_CHUNK 2048

typedef short s16x8 __attribute__((ext_vector_type(8)));
typedef float f32x4 __attribute__((ext_vector_type(4)));

__device__ inline ushort f2b(float f) {
  uint u = __float_as_uint(f);
  return (ushort)((u + 0x7fffu + ((u >> 16) & 1u)) >> 16);
}
__device__ inline float b2f(uint h) { return __uint_as_float(h << 16); }

// ---------------- convert (+inline dtype detect) + degree histogram ----------------
__global__ __launch_bounds__(256) void convert_hist_kernel(const void* __restrict__ ei,
                                                           int* __restrict__ src,
                                                           int* __restrict__ dst,
                                                           int* __restrict__ degi, int E) {
  __shared__ int sflag;
  if (threadIdx.x == 0) {
    const int* p32 = (const int*)ei;
    int is64 = 1;
#pragma unroll 4
    for (int i = 1; i < 256; i += 2)
      if (p32[i] != 0) { is64 = 0; break; }
    sflag = is64;
  }
  __syncthreads();
  int e = blockIdx.x * 256 + threadIdx.x;
  if (e >= E) return;
  int s, d;
  if (sflag) {
    const long long* p = (const long long*)ei;
    s = (int)p[e];
    d = (int)p[E + e];
  } else {
    const int* p = (const int*)ei;
    s = p[e];
    d = p[E + e];
  }
  src[e] = s;
  dst[e] = d;
  atomicAdd(&degi[d], 1);
}

// ---------------- chunk reduce (partial sums for scan) ----------------
__global__ __launch_bounds__(256) void chunk_reduce_kernel(const int* __restrict__ degi,
                                                           int* __restrict__ partials, int N) {
  __shared__ int s[256];
  int base = blockIdx.x * SCAN_CHUNK;
  int sum = 0;
  for (int j = 0; j < 8; ++j) {
    int i = base + threadIdx.x * 8 + j;
    if (i < N) sum += degi[i];
  }
  s[threadIdx.x] = sum;
  __syncthreads();
  for (int ofs = 128; ofs > 0; ofs >>= 1) {
    if ((int)threadIdx.x < ofs) s[threadIdx.x] += s[threadIdx.x + ofs];
    __syncthreads();
  }
  if (threadIdx.x == 0) partials[blockIdx.x] = s[0];
}

// ---------------- chunk scan: rowptr + dinv + zero degi (cnt prep) ----------------
__global__ __launch_bounds__(256) void chunk_scan_kernel(int* __restrict__ degi,
                                                         const int* __restrict__ partials,
                                                         int nchunk,
                                                         int* __restrict__ rowptr,
                                                         float* __restrict__ dinv,
                                                         int N, int E) {
  __shared__ int s[256];
  __shared__ int sbase;
  int t = threadIdx.x;
  if (t == 0) {
    int acc = 0;
    for (int c = 0; c < (int)blockIdx.x; ++c) acc += partials[c];
    sbase = acc;
    if (blockIdx.x == 0) rowptr[N] = E;
  }
  int base = blockIdx.x * SCAN_CHUNK;
  int v[8];
  int tsum = 0;
  for (int j = 0; j < 8; ++j) {
    int i = base + t * 8 + j;
    v[j] = (i < N) ? degi[i] : 0;
    tsum += v[j];
  }
  s[t] = tsum;
  __syncthreads();
  for (int ofs = 1; ofs < 256; ofs <<= 1) {
    int add = (t >= ofs) ? s[t - ofs] : 0;
    __syncthreads();
    s[t] += add;
    __syncthreads();
  }
  int run = s[t] - tsum + sbase;
  for (int j = 0; j < 8; ++j) {
    int i = base + t * 8 + j;
    if (i < N) {
      rowptr[i] = run;
      dinv[i] = rsqrtf((float)v[j] + 1.0f);
      degi[i] = 0;  // becomes cnt for scatter
    }
    run += v[j];
  }
}

// ---------------- counting-sort scatter: edge -> packed {src:16, norm:bf16} ----------------
__global__ __launch_bounds__(256) void scatter_kernel(const int* __restrict__ src,
                                                      const int* __restrict__ dst,
                                                      const int* __restrict__ rowptr,
                                                      const float* __restrict__ dinv,
                                                      int* __restrict__ cnt,
                                                      uint* __restrict__ epack, int E) {
  int e = blockIdx.x * 256 + threadIdx.x;
  if (e >= E) return;
  int d = dst[e];
  int s = src[e];
  int slot = rowptr[d] + atomicAdd(&cnt[d], 1);
  float nm = dinv[s] * dinv[d];
  epack[slot] = (uint)s | ((uint)f2b(nm) << 16);
}

// ---------------- fused weight prep (6 weights, hi/lo split, transpose) + x->bf16 pad ----------------
__global__ __launch_bounds__(256) void prep_all(const float* __restrict__ W1,
                                                const float* __restrict__ W2,
                                                const float* __restrict__ W3,
                                                const float* __restrict__ F1,
                                                const float* __restrict__ F2,
                                                const float* __restrict__ F3,
                                                const float* __restrict__ x,
                                                ushort* __restrict__ W1t, ushort* __restrict__ W2t,
                                                ushort* __restrict__ W3t, ushort* __restrict__ F1t,
                                                ushort* __restrict__ F2t, ushort* __restrict__ F3t,
                                                ushort* __restrict__ xb, int N) {
  int b = blockIdx.x;
  if (b < 384) {
    int wi = b >> 6;
    int i = (b & 63) * 256 + threadIdx.x;
    const float* W;
    ushort* Wt;
    int K, Kp, ncol;
    switch (wi) {
      case 0: W = W1; Wt = W1t; K = 50; Kp = 64; ncol = 128; break;
      case 1: W = W2; Wt = W2t; K = 128; Kp = 128; ncol = 128; break;
      case 2: W = W3; Wt = W3t; K = 128; Kp = 128; ncol = 128; break;
      case 3: W = F1; Wt = F1t; K = 128; Kp = 128; ncol = 128; break;
      case 4: W = F2; Wt = F2t; K = 128; Kp = 128; ncol = 128; break;
      default: W = F3; Wt = F3t; K = 128; Kp = 128; ncol = 121; break;
    }
    if (i >= 128 * Kp) return;
    int c = i / Kp, k = i - c * Kp;
    float w = (k < K && c < ncol) ? W[(size_t)k * ncol + c] : 0.f;
    ushort hi = f2b(w);
    float rem = w - b2f(hi);
    Wt[(size_t)c * Kp + k] = hi;
    Wt[(size_t)128 * Kp + (size_t)c * Kp + k] = f2b(rem);
  } else {
    long i = (long)(b - 384) * 256 + threadIdx.x;
    if (i >= (long)N * 64) return;
    int n = (int)(i >> 6), k = (int)(i & 63);
    xb[i] = (k < 50) ? f2b(x[(size_t)n * 50 + k]) : (ushort)0;
  }
}

// ---------------- MFMA matmul: Y[N x 128] = X[N x K]bf16 @ (Whi+Wlo)[K x 128] ----------------
template <int KSTEPS, bool BIAS, bool RELU, bool FINAL>
__global__ __launch_bounds__(256) void mm_mfma(const ushort* __restrict__ X,
                                               const ushort* __restrict__ Wt,
                                               const float* __restrict__ bias,
                                               ushort* __restrict__ Yb,
                                               float* __restrict__ Yf, int N) {
  constexpr int K = KSTEPS * 32;
  const int lane = threadIdx.x & 63;
  const int wid = (blockIdx.x * 256 + threadIdx.x) >> 6;
  const long r0 = (long)wid * 32;
  if (r0 >= N) return;
  const bool v1 = (r0 + 16) < N;
  const int am = lane & 15;
  const int ag = lane >> 4;
  const ushort* __restrict__ wbase = Wt + (size_t)am * K + ag * 8;
  const ushort* __restrict__ x0 = X + (size_t)(r0 + am) * K + ag * 8;

  f32x4 acc[2][8] = {};
  for (int ks = 0; ks < KSTEPS; ++ks) {
    s16x8 a0 = *(const s16x8*)(x0 + ks * 32);
    s16x8 a1 = {};
    if (v1) a1 = *(const s16x8*)(x0 + (size_t)16 * K + ks * 32);
#pragma unroll
    for (int f = 0; f < 8; ++f) {
      const ushort* wp = wbase + (size_t)f * 16 * K + ks * 32;
      s16x8 bh = *(const s16x8*)(wp);
      s16x8 bl = *(const s16x8*)(wp + (size_t)128 * K);
      acc[0][f] = __builtin_amdgcn_mfma_f32_16x16x32_bf16(a0, bh, acc[0][f], 0, 0, 0);
      acc[0][f] = __builtin_amdgcn_mfma_f32_16x16x32_bf16(a0, bl, acc[0][f], 0, 0, 0);
      if (v1) {
        acc[1][f] = __builtin_amdgcn_mfma_f32_16x16x32_bf16(a1, bh, acc[1][f], 0, 0, 0);
        acc[1][f] = __builtin_amdgcn_mfma_f32_16x16x32_bf16(a1, bl, acc[1][f], 0, 0, 0);
      }
    }
  }

  const int dr = (lane >> 4) * 4;
  const int dc = lane & 15;
#pragma unroll
  for (int m = 0; m < 2; ++m) {
    if (m == 1 && !v1) break;
#pragma unroll
    for (int f = 0; f < 8; ++f) {
      int col = f * 16 + dc;
      float bv = 0.f;
      if (BIAS) {
        if (!FINAL || col < 121) bv = bias[col];
      }
#pragma unroll
      for (int r = 0; r < 4; ++r) {
        long row = r0 + m * 16 + dr + r;
        float v = acc[m][f][r] + bv;
        if (RELU) v = fmaxf(v, 0.f);
        if (FINAL) {
          if (col < 121) Yf[row * 121 + col] = v;
        } else {
          Yb[row * 128 + col] = f2b(v);
        }
      }
    }
  }
}

// ---------------- CSR aggregation, 8-deep pipelined gather ----------------
// RW = row width in ushorts (64 or 128). RW=128: lane holds 2 features.
// RW=64: lane holds 1 feature. Record: low16 = src idx, high16 = bf16 norm.
template <int RW, bool ACT>
__global__ __launch_bounds__(256) void agg_kernel(const ushort* __restrict__ Hm,
                                                  const int* __restrict__ rowptr,
                                                  const uint* __restrict__ epack,
                                                  const float* __restrict__ dinv,
                                                  const float* __restrict__ b,
                                                  ushort* __restrict__ Y, int N) {
  int wave = threadIdx.x >> 6;
  int lane = threadIdx.x & 63;
  int n = blockIdx.x * 4 + wave;
  if (n >= N) return;
  int beg = rowptr[n], end = rowptr[n + 1];
  float dn = dinv[n];
  float d2 = dn * dn;
  int i = beg;

  if constexpr (RW == 128) {
    int f = lane * 2;
    float ax = 0.f, ay = 0.f;
    while (i + 8 <= end) {
      uint rec[8];
#pragma unroll
      for (int j = 0; j < 8; ++j) rec[j] = epack[i + j];
      uint v[8];
#pragma unroll
      for (int j = 0; j < 8; ++j)
        v[j] = *(const uint*)&Hm[(size_t)(rec[j] & 0xffffu) * 128 + f];
#pragma unroll
      for (int j = 0; j < 8; ++j) {
        float nm = __uint_as_float(rec[j] & 0xffff0000u);
        ax += b2f(v[j] & 0xffffu) * nm;
        ay += b2f(v[j] >> 16) * nm;
      }
      i += 8;
    }
    if (i + 4 <= end) {
      uint rec[4];
#pragma unroll
      for (int j = 0; j < 4; ++j) rec[j] = epack[i + j];
      uint v[4];
#pragma unroll
      for (int j = 0; j < 4; ++j)
        v[j] = *(const uint*)&Hm[(size_t)(rec[j] & 0xffffu) * 128 + f];
#pragma unroll
      for (int j = 0; j < 4; ++j) {
        float nm = __uint_as_float(rec[j] & 0xffff0000u);
        ax += b2f(v[j] & 0xffffu) * nm;
        ay += b2f(v[j] >> 16) * nm;
      }
      i += 4;
    }
    for (; i < end; ++i) {
      uint rec = epack[i];
      float nm = __uint_as_float(rec & 0xffff0000u);
      uint v = *(const uint*)&Hm[(size_t)(rec & 0xffffu) * 128 + f];
      ax += b2f(v & 0xffffu) * nm;
      ay += b2f(v >> 16) * nm;
    }
    uint sv = *(const uint*)&Hm[(size_t)n * 128 + f];
    ax += b2f(sv & 0xffffu) * d2;
    ay += b2f(sv >> 16) * d2;
    if (ACT) {
      ax = fmaxf(ax + b[f], 0.f);
      ay = fmaxf(ay + b[f + 1], 0.f);
    }
    uint out = (uint)f2b(ax) | ((uint)f2b(ay) << 16);
    *(uint*)&Y[(size_t)n * 128 + f] = out;
  } else {
    int f = lane;
    float ax = 0.f;
    while (i + 8 <= end) {
      uint rec[8];
#pragma unroll
      for (int j = 0; j < 8; ++j) rec[j] = epack[i + j];
      ushort v[8];
#pragma unroll
      for (int j = 0; j < 8; ++j)
        v[j] = Hm[(size_t)(rec[j] & 0xffffu) * 64 + f];
#pragma unroll
      for (int j = 0; j < 8; ++j)
        ax += b2f(v[j]) * __uint_as_float(rec[j] & 0xffff0000u);
      i += 8;
    }
    if (i + 4 <= end) {
      uint rec[4];
#pragma unroll
      for (int j = 0; j < 4; ++j) rec[j] = epack[i + j];
      ushort v[4];
#pragma unroll
      for (int j = 0; j < 4; ++j)
        v[j] = Hm[(size_t)(rec[j] & 0xffffu) * 64 + f];
#pragma unroll
      for (int j = 0; j < 4; ++j)
        ax += b2f(v[j]) * __uint_as_float(rec[j] & 0xffff0000u);
      i += 4;
    }
    for (; i < end; ++i) {
      uint rec = epack[i];
      ax += b2f(Hm[(size_t)(rec & 0xffffu) * 64 + f]) * __uint_as_float(rec & 0xffff0000u);
    }
    ax += b2f(Hm[(size_t)n * 64 + f]) * d2;
    if (ACT) ax = fmaxf(ax + b[f], 0.f);
    Y[(size_t)n * 64 + f] = f2b(ax);
  }
}

// ---------------- launch ----------------
extern "C" void kernel_launch(void* const* d_in, const int* in_sizes, int n_in,
                              void* d_out, int out_size, void* d_ws, size_t ws_size,
                              hipStream_t stream) {
  const float* x    = (const float*)d_in[0];
  const void*  ei   = d_in[1];
  const float* W1   = (const float*)d_in[3];
  const float* b1   = (const float*)d_in[4];
  const float* W2   = (const float*)d_in[5];
  const float* b2   = (const float*)d_in[6];
  const float* W3   = (const float*)d_in[7];
  const float* b3   = (const float*)d_in[8];
  const float* fcW1 = (const float*)d_in[9];
  const float* fcb1 = (const float*)d_in[10];
  const float* fcW2 = (const float*)d_in[11];
  const float* fcb2 = (const float*)d_in[12];
  const float* fcW3 = (const float*)d_in[13];
  const float* fcb3 = (const float*)d_in[14];

  const int FIN = 50;
  const int N = in_sizes[0] / FIN;
  const int E = in_sizes[1] / 2;
  const int NCHUNK = (N + SCAN_CHUNK - 1) / SCAN_CHUNK;

  size_t off = 0;
  auto carve = [&](size_t bytes) {
    void* p = (char*)d_ws + off;
    off += (bytes + 255) & ~(size_t)255;
    return p;
  };
  int*    src32    = (int*)carve((size_t)E * 4);
  int*    dst32    = (int*)carve((size_t)E * 4);
  uint*   epack    = (uint*)carve((size_t)E * 4);
  int*    degi     = (int*)carve((size_t)N * 4);  // later reused as cnt for scatter
  int*    rowptr   = (int*)carve((size_t)(N + 1) * 4);
  float*  dinv     = (float*)carve((size_t)N * 4);
  int*    partials = (int*)carve((size_t)NCHUNK * 4);
  ushort* W1t      = (ushort*)carve((size_t)2 * 128 * 64 * 2);
  ushort* W2t      = (ushort*)carve((size_t)2 * 128 * 128 * 2);
  ushort* W3t      = (ushort*)carve((size_t)2 * 128 * 128 * 2);
  ushort* F1t      = (ushort*)carve((size_t)2 * 128 * 128 * 2);
  ushort* F2t      = (ushort*)carve((size_t)2 * 128 * 128 * 2);
  ushort* F3t      = (ushort*)carve((size_t)2 * 128 * 128 * 2);
  ushort* xb       = (ushort*)carve((size_t)N * 64 * 2);
  ushort* aggX     = (ushort*)carve((size_t)N * 64 * 2);
  ushort* bufA     = (ushort*)carve((size_t)N * 128 * 2);
  ushort* bufB     = (ushort*)carve((size_t)N * 128 * 2);

  const int gE = (E + 255) / 256;
  const int gMM = (N + 127) / 128;
  const int gAGG = (N + 3) / 4;
  const int gPREP = 384 + (int)(((long)N * 64 + 255) / 256);

  // --- graph preprocessing ---
  hipMemsetAsync(degi, 0, (size_t)N * 4, stream);
  convert_hist_kernel<<<gE, 256, 0, stream>>>(ei, src32, dst32, degi, E);
  chunk_reduce_kernel<<<NCHUNK, 256, 0, stream>>>(degi, partials, N);
  chunk_scan_kernel<<<NCHUNK, 256, 0, stream>>>(degi, partials, NCHUNK, rowptr, dinv, N, E);
  scatter_kernel<<<gE, 256, 0, stream>>>(src32, dst32, rowptr, dinv, degi, epack, E);
  prep_all<<<gPREP, 256, 0, stream>>>(W1, W2, W3, fcW1, fcW2, fcW3, x,
                                      W1t, W2t, W3t, F1t, F2t, F3t, xb, N);

  // --- conv layer 1 (reordered: aggregate input, then mm with fused bias+relu) ---
  agg_kernel<64, false><<<gAGG, 256, 0, stream>>>(xb, rowptr, epack, dinv, nullptr, aggX, N);
  mm_mfma<2, true, true, false><<<gMM, 256, 0, stream>>>(aggX, W1t, b1, bufA, nullptr, N);
  // --- conv layer 2 ---
  mm_mfma<4, false, false, false><<<gMM, 256, 0, stream>>>(bufA, W2t, nullptr, bufB, nullptr, N);
  agg_kernel<128, true><<<gAGG, 256, 0, stream>>>(bufB, rowptr, epack, dinv, b2, bufA, N);
  // --- conv layer 3 ---
  mm_mfma<4, false, false, false><<<gMM, 256, 0, stream>>>(bufA, W3t, nullptr, bufB, nullptr, N);
  agg_kernel<128, true><<<gAGG, 256, 0, stream>>>(bufB, rowptr, epack, dinv, b3, bufA, N);
  // --- FC head ---
  mm_mfma<4, true, true, false><<<gMM, 256, 0, stream>>>(bufA, F1t, fcb1, bufB, nullptr, N);
  mm_mfma<4, true, true, false><<<gMM, 256, 0, stream>>>(bufB, F2t, fcb2, bufA, nullptr, N);
  mm_mfma<4, true, false, true><<<gMM, 256, 0, stream>>>(bufA, F3t, fcb3, nullptr, (float*)d_out, N);
}

// Round 5
// 318.288 us; speedup vs baseline: 2.5021x; 1.0099x over previous
//
#include <hip/hip_runtime.h>

#define SCAN_CHUNK 2048

typedef short s16x8 __attribute__((ext_vector_type(8)));
typedef float f32x4 __attribute__((ext_vector_type(4)));

__device__ inline ushort f2b(float f) {
  uint u = __float_as_uint(f);
  return (ushort)((u + 0x7fffu + ((u >> 16) & 1u)) >> 16);
}
__device__ inline float b2f(uint h) { return __uint_as_float(h << 16); }

// ---------------- convert (+inline dtype detect) + degree histogram ----------------
__global__ __launch_bounds__(256) void convert_hist_kernel(const void* __restrict__ ei,
                                                           int* __restrict__ src,
                                                           int* __restrict__ dst,
                                                           int* __restrict__ degi, int E) {
  __shared__ int sflag;
  if (threadIdx.x == 0) {
    const int* p32 = (const int*)ei;
    int is64 = 1;
#pragma unroll 4
    for (int i = 1; i < 256; i += 2)
      if (p32[i] != 0) { is64 = 0; break; }
    sflag = is64;
  }
  __syncthreads();
  int e = blockIdx.x * 256 + threadIdx.x;
  if (e >= E) return;
  int s, d;
  if (sflag) {
    const long long* p = (const long long*)ei;
    s = (int)p[e];
    d = (int)p[E + e];
  } else {
    const int* p = (const int*)ei;
    s = p[e];
    d = p[E + e];
  }
  src[e] = s;
  dst[e] = d;
  atomicAdd(&degi[d], 1);
}

// ---------------- chunk reduce (partial sums for scan) ----------------
__global__ __launch_bounds__(256) void chunk_reduce_kernel(const int* __restrict__ degi,
                                                           int* __restrict__ partials, int N) {
  __shared__ int s[256];
  int base = blockIdx.x * SCAN_CHUNK;
  int sum = 0;
  for (int j = 0; j < 8; ++j) {
    int i = base + threadIdx.x * 8 + j;
    if (i < N) sum += degi[i];
  }
  s[threadIdx.x] = sum;
  __syncthreads();
  for (int ofs = 128; ofs > 0; ofs >>= 1) {
    if ((int)threadIdx.x < ofs) s[threadIdx.x] += s[threadIdx.x + ofs];
    __syncthreads();
  }
  if (threadIdx.x == 0) partials[blockIdx.x] = s[0];
}

// ---------------- chunk scan: rowptr + dinv + zero degi (cnt prep) ----------------
__global__ __launch_bounds__(256) void chunk_scan_kernel(int* __restrict__ degi,
                                                         const int* __restrict__ partials,
                                                         int nchunk,
                                                         int* __restrict__ rowptr,
                                                         float* __restrict__ dinv,
                                                         int N, int E) {
  __shared__ int s[256];
  __shared__ int sbase;
  int t = threadIdx.x;
  if (t == 0) {
    int acc = 0;
    for (int c = 0; c < (int)blockIdx.x; ++c) acc += partials[c];
    sbase = acc;
    if (blockIdx.x == 0) rowptr[N] = E;
  }
  int base = blockIdx.x * SCAN_CHUNK;
  int v[8];
  int tsum = 0;
  for (int j = 0; j < 8; ++j) {
    int i = base + t * 8 + j;
    v[j] = (i < N) ? degi[i] : 0;
    tsum += v[j];
  }
  s[t] = tsum;
  __syncthreads();
  for (int ofs = 1; ofs < 256; ofs <<= 1) {
    int add = (t >= ofs) ? s[t - ofs] : 0;
    __syncthreads();
    s[t] += add;
    __syncthreads();
  }
  int run = s[t] - tsum + sbase;
  for (int j = 0; j < 8; ++j) {
    int i = base + t * 8 + j;
    if (i < N) {
      rowptr[i] = run;
      dinv[i] = rsqrtf((float)v[j] + 1.0f);
      degi[i] = 0;  // becomes cnt for scatter
    }
    run += v[j];
  }
}

// ---------------- XCD-chunked counting-sort scatter ----------------
// Write amplification killer: epack lines are dirtied by all 8 XCDs' L2s
// (~18 writebacks/line measured). Block bid only commits edges whose dst is
// in chunk (bid&7); with round-robin blockIdx->XCD each chunk's slot window
// is written by ONE XCD. Every block streams all edges (reads are L3-served).
__global__ __launch_bounds__(256) void scatter_kernel(const int* __restrict__ src,
                                                      const int* __restrict__ dst,
                                                      const int* __restrict__ rowptr,
                                                      const float* __restrict__ dinv,
                                                      int* __restrict__ cnt,
                                                      uint* __restrict__ epack, int E, int N) {
  const int chunk = blockIdx.x & 7;
  const int group = blockIdx.x >> 3;
  const int ngroup = gridDim.x >> 3;
  const int c0 = (int)(((long)chunk * N) >> 3);
  const int c1 = (int)(((long)(chunk + 1) * N) >> 3);
  for (int e = group * 256 + threadIdx.x; e < E; e += ngroup * 256) {
    int d = dst[e];
    if (d < c0 || d >= c1) continue;
    int s = src[e];
    int slot = rowptr[d] + atomicAdd(&cnt[d], 1);
    float nm = dinv[s] * dinv[d];
    epack[slot] = (uint)s | ((uint)f2b(nm) << 16);
  }
}

// ---------------- fused weight prep (6 weights, hi/lo split, transpose) + x->bf16 pad ----------------
__global__ __launch_bounds__(256) void prep_all(const float* __restrict__ W1,
                                                const float* __restrict__ W2,
                                                const float* __restrict__ W3,
                                                const float* __restrict__ F1,
                                                const float* __restrict__ F2,
                                                const float* __restrict__ F3,
                                                const float* __restrict__ x,
                                                ushort* __restrict__ W1t, ushort* __restrict__ W2t,
                                                ushort* __restrict__ W3t, ushort* __restrict__ F1t,
                                                ushort* __restrict__ F2t, ushort* __restrict__ F3t,
                                                ushort* __restrict__ xb, int N) {
  int b = blockIdx.x;
  if (b < 384) {
    int wi = b >> 6;
    int i = (b & 63) * 256 + threadIdx.x;
    const float* W;
    ushort* Wt;
    int K, Kp, ncol;
    switch (wi) {
      case 0: W = W1; Wt = W1t; K = 50; Kp = 64; ncol = 128; break;
      case 1: W = W2; Wt = W2t; K = 128; Kp = 128; ncol = 128; break;
      case 2: W = W3; Wt = W3t; K = 128; Kp = 128; ncol = 128; break;
      case 3: W = F1; Wt = F1t; K = 128; Kp = 128; ncol = 128; break;
      case 4: W = F2; Wt = F2t; K = 128; Kp = 128; ncol = 128; break;
      default: W = F3; Wt = F3t; K = 128; Kp = 128; ncol = 121; break;
    }
    if (i >= 128 * Kp) return;
    int c = i / Kp, k = i - c * Kp;
    float w = (k < K && c < ncol) ? W[(size_t)k * ncol + c] : 0.f;
    ushort hi = f2b(w);
    float rem = w - b2f(hi);
    Wt[(size_t)c * Kp + k] = hi;
    Wt[(size_t)128 * Kp + (size_t)c * Kp + k] = f2b(rem);
  } else {
    long i = (long)(b - 384) * 256 + threadIdx.x;
    if (i >= (long)N * 64) return;
    int n = (int)(i >> 6), k = (int)(i & 63);
    xb[i] = (k < 50) ? f2b(x[(size_t)n * 50 + k]) : (ushort)0;
  }
}

// ---------------- MFMA matmul: Y[N x 128] = X[N x K]bf16 @ (Whi+Wlo)[K x 128] ----------------
template <int KSTEPS, bool BIAS, bool RELU>
__global__ __launch_bounds__(256) void mm_mfma(const ushort* __restrict__ X,
                                               const ushort* __restrict__ Wt,
                                               const float* __restrict__ bias,
                                               ushort* __restrict__ Yb, int N) {
  constexpr int K = KSTEPS * 32;
  const int lane = threadIdx.x & 63;
  const int wid = (blockIdx.x * 256 + threadIdx.x) >> 6;
  const long r0 = (long)wid * 32;
  if (r0 >= N) return;
  const bool v1 = (r0 + 16) < N;
  const int am = lane & 15;
  const int ag = lane >> 4;
  const ushort* __restrict__ wbase = Wt + (size_t)am * K + ag * 8;
  const ushort* __restrict__ x0 = X + (size_t)(r0 + am) * K + ag * 8;

  f32x4 acc[2][8] = {};
  for (int ks = 0; ks < KSTEPS; ++ks) {
    s16x8 a0 = *(const s16x8*)(x0 + ks * 32);
    s16x8 a1 = {};
    if (v1) a1 = *(const s16x8*)(x0 + (size_t)16 * K + ks * 32);
#pragma unroll
    for (int f = 0; f < 8; ++f) {
      const ushort* wp = wbase + (size_t)f * 16 * K + ks * 32;
      s16x8 bh = *(const s16x8*)(wp);
      s16x8 bl = *(const s16x8*)(wp + (size_t)128 * K);
      acc[0][f] = __builtin_amdgcn_mfma_f32_16x16x32_bf16(a0, bh, acc[0][f], 0, 0, 0);
      acc[0][f] = __builtin_amdgcn_mfma_f32_16x16x32_bf16(a0, bl, acc[0][f], 0, 0, 0);
      if (v1) {
        acc[1][f] = __builtin_amdgcn_mfma_f32_16x16x32_bf16(a1, bh, acc[1][f], 0, 0, 0);
        acc[1][f] = __builtin_amdgcn_mfma_f32_16x16x32_bf16(a1, bl, acc[1][f], 0, 0, 0);
      }
    }
  }

  const int dr = (lane >> 4) * 4;
  const int dc = lane & 15;
#pragma unroll
  for (int m = 0; m < 2; ++m) {
    if (m == 1 && !v1) break;
#pragma unroll
    for (int f = 0; f < 8; ++f) {
      int col = f * 16 + dc;
      float bv = BIAS ? bias[col] : 0.f;
#pragma unroll
      for (int r = 0; r < 4; ++r) {
        long row = r0 + m * 16 + dr + r;
        float v = acc[m][f][r] + bv;
        if (RELU) v = fmaxf(v, 0.f);
        Yb[row * 128 + col] = f2b(v);
      }
    }
  }
}

// ---------------- fused FC head: relu(relu(X@F1+b1)@F2+b2)@F3+b3 ----------------
// Wave keeps its 32x128 tile on-chip; private 8KB LDS region per wave for the
// D-layout -> A-layout transpose between layers (XOR-swizzled, no syncthreads).
__global__ __launch_bounds__(256) void fc_fused(const ushort* __restrict__ X,
                                                const ushort* __restrict__ F1t,
                                                const ushort* __restrict__ F2t,
                                                const ushort* __restrict__ F3t,
                                                const float* __restrict__ b1,
                                                const float* __restrict__ b2,
                                                const float* __restrict__ b3,
                                                float* __restrict__ out, int N) {
  __shared__ ushort lds[4][32 * 128];
  const int lane = threadIdx.x & 63;
  const int wv = threadIdx.x >> 6;
  const int wid = (blockIdx.x * 256 + threadIdx.x) >> 6;
  const long r0 = (long)wid * 32;
  if (r0 >= N) return;
  const bool v1 = (r0 + 16) < N;
  const int am = lane & 15;
  const int ag = lane >> 4;
  char* my = (char*)lds[wv];

  // stage acc tile (D-layout) into LDS as bf16, swizzled
  auto stage = [&](f32x4 acc[2][8], const float* __restrict__ bias) {
#pragma unroll
    for (int m = 0; m < 2; ++m)
#pragma unroll
      for (int f = 0; f < 8; ++f) {
        int col = f * 16 + am;
        float bv = bias[col];
#pragma unroll
        for (int r = 0; r < 4; ++r) {
          int row = m * 16 + ag * 4 + r;
          uint byte = (uint)(row * 256 + col * 2) ^ ((uint)(row & 7) << 4);
          *(ushort*)(my + byte) = f2b(fmaxf(acc[m][f][r] + bv, 0.f));
        }
      }
  };
  // load A-frag (row = m*16+am, k = ks*32 + ag*8 .. +7) from swizzled LDS
  auto loadA = [&](int m, int ks) -> s16x8 {
    int row = m * 16 + am;
    uint byte = (uint)(row * 256 + ks * 64 + ag * 16) ^ ((uint)(row & 7) << 4);
    return *(const s16x8*)(my + byte);
  };
  auto layer = [&](f32x4 acc[2][8], const ushort* __restrict__ Wt, bool fromLds,
                   const ushort* __restrict__ x0) {
#pragma unroll
    for (int ks = 0; ks < 4; ++ks) {
      s16x8 a0, a1;
      if (fromLds) {
        a0 = loadA(0, ks);
        a1 = loadA(1, ks);
      } else {
        a0 = *(const s16x8*)(x0 + ks * 32);
        a1 = v1 ? *(const s16x8*)(x0 + (size_t)16 * 128 + ks * 32) : s16x8{};
      }
      const ushort* wb = Wt + (size_t)am * 128 + ag * 8;
#pragma unroll
      for (int f = 0; f < 8; ++f) {
        const ushort* wp = wb + (size_t)f * 16 * 128 + ks * 32;
        s16x8 bh = *(const s16x8*)(wp);
        s16x8 bl = *(const s16x8*)(wp + (size_t)128 * 128);
        acc[0][f] = __builtin_amdgcn_mfma_f32_16x16x32_bf16(a0, bh, acc[0][f], 0, 0, 0);
        acc[0][f] = __builtin_amdgcn_mfma_f32_16x16x32_bf16(a0, bl, acc[0][f], 0, 0, 0);
        acc[1][f] = __builtin_amdgcn_mfma_f32_16x16x32_bf16(a1, bh, acc[1][f], 0, 0, 0);
        acc[1][f] = __builtin_amdgcn_mfma_f32_16x16x32_bf16(a1, bl, acc[1][f], 0, 0, 0);
      }
    }
  };

  const ushort* x0 = X + (size_t)(r0 + am) * 128 + ag * 8;
  f32x4 acc[2][8] = {};
  layer(acc, F1t, false, x0);  // fc1
  stage(acc, b1);
  f32x4 acc2[2][8] = {};
  layer(acc2, F2t, true, nullptr);  // fc2
  stage(acc2, b2);
  f32x4 acc3[2][8] = {};
  layer(acc3, F3t, true, nullptr);  // fc3

  // final store: f32, 121 cols
#pragma unroll
  for (int m = 0; m < 2; ++m) {
    if (m == 1 && !v1) break;
#pragma unroll
    for (int f = 0; f < 8; ++f) {
      int col = f * 16 + am;
      if (col >= 121) continue;
      float bv = b3[col];
#pragma unroll
      for (int r = 0; r < 4; ++r) {
        long row = r0 + m * 16 + ag * 4 + r;
        if (row < N) out[row * 121 + col] = acc3[m][f][r] + bv;
      }
    }
  }
}

// ---------------- CSR aggregation, 8-deep pipelined gather ----------------
template <int RW, bool ACT>
__global__ __launch_bounds__(256) void agg_kernel(const ushort* __restrict__ Hm,
                                                  const int* __restrict__ rowptr,
                                                  const uint* __restrict__ epack,
                                                  const float* __restrict__ dinv,
                                                  const float* __restrict__ b,
                                                  ushort* __restrict__ Y, int N) {
  int wave = threadIdx.x >> 6;
  int lane = threadIdx.x & 63;
  int n = blockIdx.x * 4 + wave;
  if (n >= N) return;
  int beg = rowptr[n], end = rowptr[n + 1];
  float dn = dinv[n];
  float d2 = dn * dn;
  int i = beg;

  if constexpr (RW == 128) {
    int f = lane * 2;
    float ax = 0.f, ay = 0.f;
    while (i + 8 <= end) {
      uint rec[8];
#pragma unroll
      for (int j = 0; j < 8; ++j) rec[j] = epack[i + j];
      uint v[8];
#pragma unroll
      for (int j = 0; j < 8; ++j)
        v[j] = *(const uint*)&Hm[(size_t)(rec[j] & 0xffffu) * 128 + f];
#pragma unroll
      for (int j = 0; j < 8; ++j) {
        float nm = __uint_as_float(rec[j] & 0xffff0000u);
        ax += b2f(v[j] & 0xffffu) * nm;
        ay += b2f(v[j] >> 16) * nm;
      }
      i += 8;
    }
    if (i + 4 <= end) {
      uint rec[4];
#pragma unroll
      for (int j = 0; j < 4; ++j) rec[j] = epack[i + j];
      uint v[4];
#pragma unroll
      for (int j = 0; j < 4; ++j)
        v[j] = *(const uint*)&Hm[(size_t)(rec[j] & 0xffffu) * 128 + f];
#pragma unroll
      for (int j = 0; j < 4; ++j) {
        float nm = __uint_as_float(rec[j] & 0xffff0000u);
        ax += b2f(v[j] & 0xffffu) * nm;
        ay += b2f(v[j] >> 16) * nm;
      }
      i += 4;
    }
    for (; i < end; ++i) {
      uint rec = epack[i];
      float nm = __uint_as_float(rec & 0xffff0000u);
      uint v = *(const uint*)&Hm[(size_t)(rec & 0xffffu) * 128 + f];
      ax += b2f(v & 0xffffu) * nm;
      ay += b2f(v >> 16) * nm;
    }
    uint sv = *(const uint*)&Hm[(size_t)n * 128 + f];
    ax += b2f(sv & 0xffffu) * d2;
    ay += b2f(sv >> 16) * d2;
    if (ACT) {
      ax = fmaxf(ax + b[f], 0.f);
      ay = fmaxf(ay + b[f + 1], 0.f);
    }
    uint out = (uint)f2b(ax) | ((uint)f2b(ay) << 16);
    *(uint*)&Y[(size_t)n * 128 + f] = out;
  } else {
    int f = lane;
    float ax = 0.f;
    while (i + 8 <= end) {
      uint rec[8];
#pragma unroll
      for (int j = 0; j < 8; ++j) rec[j] = epack[i + j];
      ushort v[8];
#pragma unroll
      for (int j = 0; j < 8; ++j)
        v[j] = Hm[(size_t)(rec[j] & 0xffffu) * 64 + f];
#pragma unroll
      for (int j = 0; j < 8; ++j)
        ax += b2f(v[j]) * __uint_as_float(rec[j] & 0xffff0000u);
      i += 8;
    }
    if (i + 4 <= end) {
      uint rec[4];
#pragma unroll
      for (int j = 0; j < 4; ++j) rec[j] = epack[i + j];
      ushort v[4];
#pragma unroll
      for (int j = 0; j < 4; ++j)
        v[j] = Hm[(size_t)(rec[j] & 0xffffu) * 64 + f];
#pragma unroll
      for (int j = 0; j < 4; ++j)
        ax += b2f(v[j]) * __uint_as_float(rec[j] & 0xffff0000u);
      i += 4;
    }
    for (; i < end; ++i) {
      uint rec = epack[i];
      ax += b2f(Hm[(size_t)(rec & 0xffffu) * 64 + f]) * __uint_as_float(rec & 0xffff0000u);
    }
    ax += b2f(Hm[(size_t)n * 64 + f]) * d2;
    if (ACT) ax = fmaxf(ax + b[f], 0.f);
    Y[(size_t)n * 64 + f] = f2b(ax);
  }
}

// ---------------- launch ----------------
extern "C" void kernel_launch(void* const* d_in, const int* in_sizes, int n_in,
                              void* d_out, int out_size, void* d_ws, size_t ws_size,
                              hipStream_t stream) {
  const float* x    = (const float*)d_in[0];
  const void*  ei   = d_in[1];
  const float* W1   = (const float*)d_in[3];
  const float* b1   = (const float*)d_in[4];
  const float* W2   = (const float*)d_in[5];
  const float* b2   = (const float*)d_in[6];
  const float* W3   = (const float*)d_in[7];
  const float* b3   = (const float*)d_in[8];
  const float* fcW1 = (const float*)d_in[9];
  const float* fcb1 = (const float*)d_in[10];
  const float* fcW2 = (const float*)d_in[11];
  const float* fcb2 = (const float*)d_in[12];
  const float* fcW3 = (const float*)d_in[13];
  const float* fcb3 = (const float*)d_in[14];

  const int FIN = 50;
  const int N = in_sizes[0] / FIN;
  const int E = in_sizes[1] / 2;
  const int NCHUNK = (N + SCAN_CHUNK - 1) / SCAN_CHUNK;

  size_t off = 0;
  auto carve = [&](size_t bytes) {
    void* p = (char*)d_ws + off;
    off += (bytes + 255) & ~(size_t)255;
    return p;
  };
  int*    src32    = (int*)carve((size_t)E * 4);
  int*    dst32    = (int*)carve((size_t)E * 4);
  uint*   epack    = (uint*)carve((size_t)E * 4);
  int*    degi     = (int*)carve((size_t)N * 4);  // later reused as cnt for scatter
  int*    rowptr   = (int*)carve((size_t)(N + 1) * 4);
  float*  dinv     = (float*)carve((size_t)N * 4);
  int*    partials = (int*)carve((size_t)NCHUNK * 4);
  ushort* W1t      = (ushort*)carve((size_t)2 * 128 * 64 * 2);
  ushort* W2t      = (ushort*)carve((size_t)2 * 128 * 128 * 2);
  ushort* W3t      = (ushort*)carve((size_t)2 * 128 * 128 * 2);
  ushort* F1t      = (ushort*)carve((size_t)2 * 128 * 128 * 2);
  ushort* F2t      = (ushort*)carve((size_t)2 * 128 * 128 * 2);
  ushort* F3t      = (ushort*)carve((size_t)2 * 128 * 128 * 2);
  ushort* xb       = (ushort*)carve((size_t)N * 64 * 2);
  ushort* aggX     = (ushort*)carve((size_t)N * 64 * 2);
  ushort* bufA     = (ushort*)carve((size_t)N * 128 * 2);
  ushort* bufB     = (ushort*)carve((size_t)N * 128 * 2);

  const int gE = (E + 255) / 256;
  const int gMM = (N + 127) / 128;
  const int gAGG = (N + 3) / 4;
  const int gPREP = 384 + (int)(((long)N * 64 + 255) / 256);

  // --- graph preprocessing ---
  hipMemsetAsync(degi, 0, (size_t)N * 4, stream);
  convert_hist_kernel<<<gE, 256, 0, stream>>>(ei, src32, dst32, degi, E);
  chunk_reduce_kernel<<<NCHUNK, 256, 0, stream>>>(degi, partials, N);
  chunk_scan_kernel<<<NCHUNK, 256, 0, stream>>>(degi, partials, NCHUNK, rowptr, dinv, N, E);
  scatter_kernel<<<1024, 256, 0, stream>>>(src32, dst32, rowptr, dinv, degi, epack, E, N);
  prep_all<<<gPREP, 256, 0, stream>>>(W1, W2, W3, fcW1, fcW2, fcW3, x,
                                      W1t, W2t, W3t, F1t, F2t, F3t, xb, N);

  // --- conv layer 1 (aggregate 64-wide input, then mm with fused bias+relu) ---
  agg_kernel<64, false><<<gAGG, 256, 0, stream>>>(xb, rowptr, epack, dinv, nullptr, aggX, N);
  mm_mfma<2, true, true><<<gMM, 256, 0, stream>>>(aggX, W1t, b1, bufA, N);
  // --- conv layer 2 ---
  mm_mfma<4, false, false><<<gMM, 256, 0, stream>>>(bufA, W2t, nullptr, bufB, N);
  agg_kernel<128, true><<<gAGG, 256, 0, stream>>>(bufB, rowptr, epack, dinv, b2, bufA, N);
  // --- conv layer 3 ---
  mm_mfma<4, false, false><<<gMM, 256, 0, stream>>>(bufA, W3t, nullptr, bufB, N);
  agg_kernel<128, true><<<gAGG, 256, 0, stream>>>(bufB, rowptr, epack, dinv, b3, bufA, N);
  // --- fused FC head ---
  fc_fused<<<gMM, 256, 0, stream>>>(bufA, F1t, F2t, F3t, fcb1, fcb2, fcb3,
                                    (float*)d_out, N);
}

// Round 6
// 307.227 us; speedup vs baseline: 2.5922x; 1.0360x over previous
//
#include <hip/hip_runtime.h>

#define SCAN_CHUNK 2048

typedef short s16x8 __attribute__((ext_vector_type(8)));
typedef float f32x4 __attribute__((ext_vector_type(4)));

__device__ inline ushort f2b(float f) {
  uint u = __float_as_uint(f);
  return (ushort)((u + 0x7fffu + ((u >> 16) & 1u)) >> 16);
}
__device__ inline float b2f(uint h) { return __uint_as_float(h << 16); }

// ---------------- convert (+inline dtype detect) + degree histogram ----------------
__global__ __launch_bounds__(256) void convert_hist_kernel(const void* __restrict__ ei,
                                                           int* __restrict__ src,
                                                           int* __restrict__ dst,
                                                           int* __restrict__ degi, int E) {
  __shared__ int sflag;
  if (threadIdx.x == 0) {
    const int* p32 = (const int*)ei;
    int is64 = 1;
#pragma unroll 4
    for (int i = 1; i < 256; i += 2)
      if (p32[i] != 0) { is64 = 0; break; }
    sflag = is64;
  }
  __syncthreads();
  int e = blockIdx.x * 256 + threadIdx.x;
  if (e >= E) return;
  int s, d;
  if (sflag) {
    const long long* p = (const long long*)ei;
    s = (int)p[e];
    d = (int)p[E + e];
  } else {
    const int* p = (const int*)ei;
    s = p[e];
    d = p[E + e];
  }
  src[e] = s;
  dst[e] = d;
  atomicAdd(&degi[d], 1);
}

// ---------------- chunk reduce (partial sums for scan) ----------------
__global__ __launch_bounds__(256) void chunk_reduce_kernel(const int* __restrict__ degi,
                                                           int* __restrict__ partials, int N) {
  __shared__ int s[256];
  int base = blockIdx.x * SCAN_CHUNK;
  int sum = 0;
  for (int j = 0; j < 8; ++j) {
    int i = base + threadIdx.x * 8 + j;
    if (i < N) sum += degi[i];
  }
  s[threadIdx.x] = sum;
  __syncthreads();
  for (int ofs = 128; ofs > 0; ofs >>= 1) {
    if ((int)threadIdx.x < ofs) s[threadIdx.x] += s[threadIdx.x + ofs];
    __syncthreads();
  }
  if (threadIdx.x == 0) partials[blockIdx.x] = s[0];
}

// ---------------- chunk scan: rowptr + dinv + zero degi (cnt prep) ----------------
__global__ __launch_bounds__(256) void chunk_scan_kernel(int* __restrict__ degi,
                                                         const int* __restrict__ partials,
                                                         int nchunk,
                                                         int* __restrict__ rowptr,
                                                         float* __restrict__ dinv,
                                                         int N, int E) {
  __shared__ int s[256];
  __shared__ int sbase;
  int t = threadIdx.x;
  if (t == 0) {
    int acc = 0;
    for (int c = 0; c < (int)blockIdx.x; ++c) acc += partials[c];
    sbase = acc;
    if (blockIdx.x == 0) rowptr[N] = E;
  }
  int base = blockIdx.x * SCAN_CHUNK;
  int v[8];
  int tsum = 0;
  for (int j = 0; j < 8; ++j) {
    int i = base + t * 8 + j;
    v[j] = (i < N) ? degi[i] : 0;
    tsum += v[j];
  }
  s[t] = tsum;
  __syncthreads();
  for (int ofs = 1; ofs < 256; ofs <<= 1) {
    int add = (t >= ofs) ? s[t - ofs] : 0;
    __syncthreads();
    s[t] += add;
    __syncthreads();
  }
  int run = s[t] - tsum + sbase;
  for (int j = 0; j < 8; ++j) {
    int i = base + t * 8 + j;
    if (i < N) {
      rowptr[i] = run;
      dinv[i] = rsqrtf((float)v[j] + 1.0f);
      degi[i] = 0;  // becomes cnt for scatter
    }
    run += v[j];
  }
}

// ---------------- XCD-chunked counting-sort scatter ----------------
__global__ __launch_bounds__(256) void scatter_kernel(const int* __restrict__ src,
                                                      const int* __restrict__ dst,
                                                      const int* __restrict__ rowptr,
                                                      const float* __restrict__ dinv,
                                                      int* __restrict__ cnt,
                                                      uint* __restrict__ epack, int E, int N) {
  const int chunk = blockIdx.x & 7;
  const int group = blockIdx.x >> 3;
  const int ngroup = gridDim.x >> 3;
  const int c0 = (int)(((long)chunk * N) >> 3);
  const int c1 = (int)(((long)(chunk + 1) * N) >> 3);
  for (int e = group * 256 + threadIdx.x; e < E; e += ngroup * 256) {
    int d = dst[e];
    if (d < c0 || d >= c1) continue;
    int s = src[e];
    int slot = rowptr[d] + atomicAdd(&cnt[d], 1);
    float nm = dinv[s] * dinv[d];
    epack[slot] = (uint)s | ((uint)f2b(nm) << 16);
  }
}

// ---------------- fused weight prep (6 weights, hi/lo split, transpose) + x->bf16 pad ----------------
__global__ __launch_bounds__(256) void prep_all(const float* __restrict__ W1,
                                                const float* __restrict__ W2,
                                                const float* __restrict__ W3,
                                                const float* __restrict__ F1,
                                                const float* __restrict__ F2,
                                                const float* __restrict__ F3,
                                                const float* __restrict__ x,
                                                ushort* __restrict__ W1t, ushort* __restrict__ W2t,
                                                ushort* __restrict__ W3t, ushort* __restrict__ F1t,
                                                ushort* __restrict__ F2t, ushort* __restrict__ F3t,
                                                ushort* __restrict__ xb, int N) {
  int b = blockIdx.x;
  if (b < 384) {
    int wi = b >> 6;
    int i = (b & 63) * 256 + threadIdx.x;
    const float* W;
    ushort* Wt;
    int K, Kp, ncol;
    switch (wi) {
      case 0: W = W1; Wt = W1t; K = 50; Kp = 64; ncol = 128; break;
      case 1: W = W2; Wt = W2t; K = 128; Kp = 128; ncol = 128; break;
      case 2: W = W3; Wt = W3t; K = 128; Kp = 128; ncol = 128; break;
      case 3: W = F1; Wt = F1t; K = 128; Kp = 128; ncol = 128; break;
      case 4: W = F2; Wt = F2t; K = 128; Kp = 128; ncol = 128; break;
      default: W = F3; Wt = F3t; K = 128; Kp = 128; ncol = 121; break;
    }
    if (i >= 128 * Kp) return;
    int c = i / Kp, k = i - c * Kp;
    float w = (k < K && c < ncol) ? W[(size_t)k * ncol + c] : 0.f;
    ushort hi = f2b(w);
    float rem = w - b2f(hi);
    Wt[(size_t)c * Kp + k] = hi;
    Wt[(size_t)128 * Kp + (size_t)c * Kp + k] = f2b(rem);
  } else {
    long i = (long)(b - 384) * 256 + threadIdx.x;
    if (i >= (long)N * 64) return;
    int n = (int)(i >> 6), k = (int)(i & 63);
    xb[i] = (k < 50) ? f2b(x[(size_t)n * 50 + k]) : (ushort)0;
  }
}

// ---------------- MFMA matmul, col-split: wave = 32 rows x 32 cols ----------------
// Block = 4 waves covering one 32-row tile, wave wq handles cols wq*32..wq*32+31.
// Grid = ceil(N/32) = 1563 blocks -> ~6 waves/SIMD (was 391 blocks / 1.5 waves/SIMD).
template <int KSTEPS, bool BIAS, bool RELU>
__global__ __launch_bounds__(256) void mm_mfma(const ushort* __restrict__ X,
                                               const ushort* __restrict__ Wt,
                                               const float* __restrict__ bias,
                                               ushort* __restrict__ Yb, int N) {
  constexpr int K = KSTEPS * 32;
  const int lane = threadIdx.x & 63;
  const int wq = threadIdx.x >> 6;  // col quarter
  const long r0 = (long)blockIdx.x * 32;
  if (r0 >= N) return;
  const bool v1 = (r0 + 16) < N;
  const int am = lane & 15;
  const int ag = lane >> 4;
  const ushort* __restrict__ x0 = X + (size_t)(r0 + am) * K + ag * 8;

  f32x4 acc[2][2] = {};
  for (int ks = 0; ks < KSTEPS; ++ks) {
    s16x8 a0 = *(const s16x8*)(x0 + ks * 32);
    s16x8 a1 = {};
    if (v1) a1 = *(const s16x8*)(x0 + (size_t)16 * K + ks * 32);
#pragma unroll
    for (int f = 0; f < 2; ++f) {
      const ushort* wp = Wt + (size_t)(wq * 32 + f * 16 + am) * K + ag * 8 + ks * 32;
      s16x8 bh = *(const s16x8*)(wp);
      s16x8 bl = *(const s16x8*)(wp + (size_t)128 * K);
      acc[0][f] = __builtin_amdgcn_mfma_f32_16x16x32_bf16(a0, bh, acc[0][f], 0, 0, 0);
      acc[0][f] = __builtin_amdgcn_mfma_f32_16x16x32_bf16(a0, bl, acc[0][f], 0, 0, 0);
      if (v1) {
        acc[1][f] = __builtin_amdgcn_mfma_f32_16x16x32_bf16(a1, bh, acc[1][f], 0, 0, 0);
        acc[1][f] = __builtin_amdgcn_mfma_f32_16x16x32_bf16(a1, bl, acc[1][f], 0, 0, 0);
      }
    }
  }

  const int dr = ag * 4;
#pragma unroll
  for (int m = 0; m < 2; ++m) {
    if (m == 1 && !v1) break;
#pragma unroll
    for (int f = 0; f < 2; ++f) {
      int col = wq * 32 + f * 16 + am;
      float bv = BIAS ? bias[col] : 0.f;
#pragma unroll
      for (int r = 0; r < 4; ++r) {
        long row = r0 + m * 16 + dr + r;
        float v = acc[m][f][r] + bv;
        if (RELU) v = fmaxf(v, 0.f);
        Yb[row * 128 + col] = f2b(v);
      }
    }
  }
}

// ---------------- fused FC head, col-split: 4 waves share one 32x128 LDS tile ----------------
__global__ __launch_bounds__(256) void fc_fused(const ushort* __restrict__ X,
                                                const ushort* __restrict__ F1t,
                                                const ushort* __restrict__ F2t,
                                                const ushort* __restrict__ F3t,
                                                const float* __restrict__ b1,
                                                const float* __restrict__ b2,
                                                const float* __restrict__ b3,
                                                float* __restrict__ out, int N) {
  __shared__ ushort lds[32 * 128];  // 8 KB shared tile, XOR-swizzled
  const int lane = threadIdx.x & 63;
  const int wq = threadIdx.x >> 6;
  const long r0 = (long)blockIdx.x * 32;
  if (r0 >= N) return;  // whole block shares one row tile -> uniform exit
  const bool v1 = (r0 + 16) < N;
  const int am = lane & 15;
  const int ag = lane >> 4;
  char* my = (char*)lds;

  // stage this wave's 32x32 quarter (D-layout) into the shared tile, bf16+swizzle
  auto stage = [&](f32x4 acc[2][2], const float* __restrict__ bias) {
#pragma unroll
    for (int m = 0; m < 2; ++m)
#pragma unroll
      for (int f = 0; f < 2; ++f) {
        int col = wq * 32 + f * 16 + am;
        float bv = bias[col];
#pragma unroll
        for (int r = 0; r < 4; ++r) {
          int row = m * 16 + ag * 4 + r;
          uint byte = (uint)(row * 256 + col * 2) ^ ((uint)(row & 7) << 4);
          *(ushort*)(my + byte) = f2b(fmaxf(acc[m][f][r] + bv, 0.f));
        }
      }
  };
  // load A-frag (row = m*16+am, k = ks*32 + ag*8..+7) from swizzled LDS
  auto loadA = [&](int m, int ks) -> s16x8 {
    int row = m * 16 + am;
    uint byte = (uint)(row * 256 + ks * 64 + ag * 16) ^ ((uint)(row & 7) << 4);
    return *(const s16x8*)(my + byte);
  };
  auto layer = [&](f32x4 acc[2][2], const ushort* __restrict__ Wt, bool fromLds,
                   const ushort* __restrict__ x0) {
#pragma unroll
    for (int ks = 0; ks < 4; ++ks) {
      s16x8 a0, a1;
      if (fromLds) {
        a0 = loadA(0, ks);
        a1 = loadA(1, ks);
      } else {
        a0 = *(const s16x8*)(x0 + ks * 32);
        a1 = v1 ? *(const s16x8*)(x0 + (size_t)16 * 128 + ks * 32) : s16x8{};
      }
#pragma unroll
      for (int f = 0; f < 2; ++f) {
        const ushort* wp = Wt + (size_t)(wq * 32 + f * 16 + am) * 128 + ag * 8 + ks * 32;
        s16x8 bh = *(const s16x8*)(wp);
        s16x8 bl = *(const s16x8*)(wp + (size_t)128 * 128);
        acc[0][f] = __builtin_amdgcn_mfma_f32_16x16x32_bf16(a0, bh, acc[0][f], 0, 0, 0);
        acc[0][f] = __builtin_amdgcn_mfma_f32_16x16x32_bf16(a0, bl, acc[0][f], 0, 0, 0);
        acc[1][f] = __builtin_amdgcn_mfma_f32_16x16x32_bf16(a1, bh, acc[1][f], 0, 0, 0);
        acc[1][f] = __builtin_amdgcn_mfma_f32_16x16x32_bf16(a1, bl, acc[1][f], 0, 0, 0);
      }
    }
  };

  const ushort* x0 = X + (size_t)(r0 + am) * 128 + ag * 8;
  f32x4 a1c[2][2] = {};
  layer(a1c, F1t, false, x0);  // fc1
  stage(a1c, b1);
  __syncthreads();
  f32x4 a2c[2][2] = {};
  layer(a2c, F2t, true, nullptr);  // fc2
  __syncthreads();  // all LDS reads done before overwrite
  stage(a2c, b2);
  __syncthreads();
  f32x4 a3c[2][2] = {};
  layer(a3c, F3t, true, nullptr);  // fc3

  // final store: f32, 121 cols
#pragma unroll
  for (int m = 0; m < 2; ++m) {
    if (m == 1 && !v1) break;
#pragma unroll
    for (int f = 0; f < 2; ++f) {
      int col = wq * 32 + f * 16 + am;
      if (col >= 121) continue;
      float bv = b3[col];
#pragma unroll
      for (int r = 0; r < 4; ++r) {
        long row = r0 + m * 16 + ag * 4 + r;
        if (row < N) out[row * 121 + col] = a3c[m][f][r] + bv;
      }
    }
  }
}

// ---------------- CSR aggregation, 8-deep pipelined gather ----------------
template <int RW, bool ACT>
__global__ __launch_bounds__(256) void agg_kernel(const ushort* __restrict__ Hm,
                                                  const int* __restrict__ rowptr,
                                                  const uint* __restrict__ epack,
                                                  const float* __restrict__ dinv,
                                                  const float* __restrict__ b,
                                                  ushort* __restrict__ Y, int N) {
  int wave = threadIdx.x >> 6;
  int lane = threadIdx.x & 63;
  int n = blockIdx.x * 4 + wave;
  if (n >= N) return;
  int beg = rowptr[n], end = rowptr[n + 1];
  float dn = dinv[n];
  float d2 = dn * dn;
  int i = beg;

  if constexpr (RW == 128) {
    int f = lane * 2;
    float ax = 0.f, ay = 0.f;
    while (i + 8 <= end) {
      uint rec[8];
#pragma unroll
      for (int j = 0; j < 8; ++j) rec[j] = epack[i + j];
      uint v[8];
#pragma unroll
      for (int j = 0; j < 8; ++j)
        v[j] = *(const uint*)&Hm[(size_t)(rec[j] & 0xffffu) * 128 + f];
#pragma unroll
      for (int j = 0; j < 8; ++j) {
        float nm = __uint_as_float(rec[j] & 0xffff0000u);
        ax += b2f(v[j] & 0xffffu) * nm;
        ay += b2f(v[j] >> 16) * nm;
      }
      i += 8;
    }
    if (i + 4 <= end) {
      uint rec[4];
#pragma unroll
      for (int j = 0; j < 4; ++j) rec[j] = epack[i + j];
      uint v[4];
#pragma unroll
      for (int j = 0; j < 4; ++j)
        v[j] = *(const uint*)&Hm[(size_t)(rec[j] & 0xffffu) * 128 + f];
#pragma unroll
      for (int j = 0; j < 4; ++j) {
        float nm = __uint_as_float(rec[j] & 0xffff0000u);
        ax += b2f(v[j] & 0xffffu) * nm;
        ay += b2f(v[j] >> 16) * nm;
      }
      i += 4;
    }
    for (; i < end; ++i) {
      uint rec = epack[i];
      float nm = __uint_as_float(rec & 0xffff0000u);
      uint v = *(const uint*)&Hm[(size_t)(rec & 0xffffu) * 128 + f];
      ax += b2f(v & 0xffffu) * nm;
      ay += b2f(v >> 16) * nm;
    }
    uint sv = *(const uint*)&Hm[(size_t)n * 128 + f];
    ax += b2f(sv & 0xffffu) * d2;
    ay += b2f(sv >> 16) * d2;
    if (ACT) {
      ax = fmaxf(ax + b[f], 0.f);
      ay = fmaxf(ay + b[f + 1], 0.f);
    }
    uint out = (uint)f2b(ax) | ((uint)f2b(ay) << 16);
    *(uint*)&Y[(size_t)n * 128 + f] = out;
  } else {
    int f = lane;
    float ax = 0.f;
    while (i + 8 <= end) {
      uint rec[8];
#pragma unroll
      for (int j = 0; j < 8; ++j) rec[j] = epack[i + j];
      ushort v[8];
#pragma unroll
      for (int j = 0; j < 8; ++j)
        v[j] = Hm[(size_t)(rec[j] & 0xffffu) * 64 + f];
#pragma unroll
      for (int j = 0; j < 8; ++j)
        ax += b2f(v[j]) * __uint_as_float(rec[j] & 0xffff0000u);
      i += 8;
    }
    if (i + 4 <= end) {
      uint rec[4];
#pragma unroll
      for (int j = 0; j < 4; ++j) rec[j] = epack[i + j];
      ushort v[4];
#pragma unroll
      for (int j = 0; j < 4; ++j)
        v[j] = Hm[(size_t)(rec[j] & 0xffffu) * 64 + f];
#pragma unroll
      for (int j = 0; j < 4; ++j)
        ax += b2f(v[j]) * __uint_as_float(rec[j] & 0xffff0000u);
      i += 4;
    }
    for (; i < end; ++i) {
      uint rec = epack[i];
      ax += b2f(Hm[(size_t)(rec & 0xffffu) * 64 + f]) * __uint_as_float(rec & 0xffff0000u);
    }
    ax += b2f(Hm[(size_t)n * 64 + f]) * d2;
    if (ACT) ax = fmaxf(ax + b[f], 0.f);
    Y[(size_t)n * 64 + f] = f2b(ax);
  }
}

// ---------------- launch ----------------
extern "C" void kernel_launch(void* const* d_in, const int* in_sizes, int n_in,
                              void* d_out, int out_size, void* d_ws, size_t ws_size,
                              hipStream_t stream) {
  const float* x    = (const float*)d_in[0];
  const void*  ei   = d_in[1];
  const float* W1   = (const float*)d_in[3];
  const float* b1   = (const float*)d_in[4];
  const float* W2   = (const float*)d_in[5];
  const float* b2   = (const float*)d_in[6];
  const float* W3   = (const float*)d_in[7];
  const float* b3   = (const float*)d_in[8];
  const float* fcW1 = (const float*)d_in[9];
  const float* fcb1 = (const float*)d_in[10];
  const float* fcW2 = (const float*)d_in[11];
  const float* fcb2 = (const float*)d_in[12];
  const float* fcW3 = (const float*)d_in[13];
  const float* fcb3 = (const float*)d_in[14];

  const int FIN = 50;
  const int N = in_sizes[0] / FIN;
  const int E = in_sizes[1] / 2;
  const int NCHUNK = (N + SCAN_CHUNK - 1) / SCAN_CHUNK;

  size_t off = 0;
  auto carve = [&](size_t bytes) {
    void* p = (char*)d_ws + off;
    off += (bytes + 255) & ~(size_t)255;
    return p;
  };
  int*    src32    = (int*)carve((size_t)E * 4);
  int*    dst32    = (int*)carve((size_t)E * 4);
  uint*   epack    = (uint*)carve((size_t)E * 4);
  int*    degi     = (int*)carve((size_t)N * 4);  // later reused as cnt for scatter
  int*    rowptr   = (int*)carve((size_t)(N + 1) * 4);
  float*  dinv     = (float*)carve((size_t)N * 4);
  int*    partials = (int*)carve((size_t)NCHUNK * 4);
  ushort* W1t      = (ushort*)carve((size_t)2 * 128 * 64 * 2);
  ushort* W2t      = (ushort*)carve((size_t)2 * 128 * 128 * 2);
  ushort* W3t      = (ushort*)carve((size_t)2 * 128 * 128 * 2);
  ushort* F1t      = (ushort*)carve((size_t)2 * 128 * 128 * 2);
  ushort* F2t      = (ushort*)carve((size_t)2 * 128 * 128 * 2);
  ushort* F3t      = (ushort*)carve((size_t)2 * 128 * 128 * 2);
  ushort* xb       = (ushort*)carve((size_t)N * 64 * 2);
  ushort* aggX     = (ushort*)carve((size_t)N * 64 * 2);
  ushort* bufA     = (ushort*)carve((size_t)N * 128 * 2);
  ushort* bufB     = (ushort*)carve((size_t)N * 128 * 2);

  const int gE = (E + 255) / 256;
  const int gMM = (N + 31) / 32;  // one 32-row tile per 4-wave block (col-split)
  const int gAGG = (N + 3) / 4;
  const int gPREP = 384 + (int)(((long)N * 64 + 255) / 256);

  // --- graph preprocessing ---
  hipMemsetAsync(degi, 0, (size_t)N * 4, stream);
  convert_hist_kernel<<<gE, 256, 0, stream>>>(ei, src32, dst32, degi, E);
  chunk_reduce_kernel<<<NCHUNK, 256, 0, stream>>>(degi, partials, N);
  chunk_scan_kernel<<<NCHUNK, 256, 0, stream>>>(degi, partials, NCHUNK, rowptr, dinv, N, E);
  scatter_kernel<<<1024, 256, 0, stream>>>(src32, dst32, rowptr, dinv, degi, epack, E, N);
  prep_all<<<gPREP, 256, 0, stream>>>(W1, W2, W3, fcW1, fcW2, fcW3, x,
                                      W1t, W2t, W3t, F1t, F2t, F3t, xb, N);

  // --- conv layer 1 (aggregate 64-wide input, then mm with fused bias+relu) ---
  agg_kernel<64, false><<<gAGG, 256, 0, stream>>>(xb, rowptr, epack, dinv, nullptr, aggX, N);
  mm_mfma<2, true, true><<<gMM, 256, 0, stream>>>(aggX, W1t, b1, bufA, N);
  // --- conv layer 2 ---
  mm_mfma<4, false, false><<<gMM, 256, 0, stream>>>(bufA, W2t, nullptr, bufB, N);
  agg_kernel<128, true><<<gAGG, 256, 0, stream>>>(bufB, rowptr, epack, dinv, b2, bufA, N);
  // --- conv layer 3 ---
  mm_mfma<4, false, false><<<gMM, 256, 0, stream>>>(bufA, W3t, nullptr, bufB, N);
  agg_kernel<128, true><<<gAGG, 256, 0, stream>>>(bufB, rowptr, epack, dinv, b3, bufA, N);
  // --- fused FC head ---
  fc_fused<<<gMM, 256, 0, stream>>>(bufA, F1t, F2t, F3t, fcb1, fcb2, fcb3,
                                    (float*)d_out, N);
}

// Round 7
// 259.790 us; speedup vs baseline: 3.0655x; 1.1826x over previous
//
#include <hip/hip_runtime.h>

#define SCAN_CHUNK 2048

typedef short s16x8 __attribute__((ext_vector_type(8)));
typedef float f32x4 __attribute__((ext_vector_type(4)));

__device__ inline ushort f2b(float f) {
  uint u = __float_as_uint(f);
  return (ushort)((u + 0x7fffu + ((u >> 16) & 1u)) >> 16);
}
__device__ inline float b2f(uint h) { return __uint_as_float(h << 16); }

// ---------------- convert (+inline dtype detect) + degree histogram ----------------
__global__ __launch_bounds__(256) void convert_hist_kernel(const void* __restrict__ ei,
                                                           int* __restrict__ src,
                                                           int* __restrict__ dst,
                                                           int* __restrict__ degi, int E) {
  __shared__ int sflag;
  if (threadIdx.x == 0) {
    const int* p32 = (const int*)ei;
    int is64 = 1;
#pragma unroll 4
    for (int i = 1; i < 256; i += 2)
      if (p32[i] != 0) { is64 = 0; break; }
    sflag = is64;
  }
  __syncthreads();
  int e = blockIdx.x * 256 + threadIdx.x;
  if (e >= E) return;
  int s, d;
  if (sflag) {
    const long long* p = (const long long*)ei;
    s = (int)p[e];
    d = (int)p[E + e];
  } else {
    const int* p = (const int*)ei;
    s = p[e];
    d = p[E + e];
  }
  src[e] = s;
  dst[e] = d;
  atomicAdd(&degi[d], 1);
}

// ---------------- chunk reduce (partial sums for scan) ----------------
__global__ __launch_bounds__(256) void chunk_reduce_kernel(const int* __restrict__ degi,
                                                           int* __restrict__ partials, int N) {
  __shared__ int s[256];
  int base = blockIdx.x * SCAN_CHUNK;
  int sum = 0;
  for (int j = 0; j < 8; ++j) {
    int i = base + threadIdx.x * 8 + j;
    if (i < N) sum += degi[i];
  }
  s[threadIdx.x] = sum;
  __syncthreads();
  for (int ofs = 128; ofs > 0; ofs >>= 1) {
    if ((int)threadIdx.x < ofs) s[threadIdx.x] += s[threadIdx.x + ofs];
    __syncthreads();
  }
  if (threadIdx.x == 0) partials[blockIdx.x] = s[0];
}

// ---------------- chunk scan: rowptr + dinv + zero degi (cnt prep) ----------------
__global__ __launch_bounds__(256) void chunk_scan_kernel(int* __restrict__ degi,
                                                         const int* __restrict__ partials,
                                                         int nchunk,
                                                         int* __restrict__ rowptr,
                                                         float* __restrict__ dinv,
                                                         int N, int E) {
  __shared__ int s[256];
  __shared__ int sbase;
  int t = threadIdx.x;
  if (t == 0) {
    int acc = 0;
    for (int c = 0; c < (int)blockIdx.x; ++c) acc += partials[c];
    sbase = acc;
    if (blockIdx.x == 0) rowptr[N] = E;
  }
  int base = blockIdx.x * SCAN_CHUNK;
  int v[8];
  int tsum = 0;
  for (int j = 0; j < 8; ++j) {
    int i = base + t * 8 + j;
    v[j] = (i < N) ? degi[i] : 0;
    tsum += v[j];
  }
  s[t] = tsum;
  __syncthreads();
  for (int ofs = 1; ofs < 256; ofs <<= 1) {
    int add = (t >= ofs) ? s[t - ofs] : 0;
    __syncthreads();
    s[t] += add;
    __syncthreads();
  }
  int run = s[t] - tsum + sbase;
  for (int j = 0; j < 8; ++j) {
    int i = base + t * 8 + j;
    if (i < N) {
      rowptr[i] = run;
      dinv[i] = rsqrtf((float)v[j] + 1.0f);
      degi[i] = 0;  // becomes cnt for scatter
    }
    run += v[j];
  }
}

// ---------------- XCD-chunked counting-sort scatter ----------------
__global__ __launch_bounds__(256) void scatter_kernel(const int* __restrict__ src,
                                                      const int* __restrict__ dst,
                                                      const int* __restrict__ rowptr,
                                                      const float* __restrict__ dinv,
                                                      int* __restrict__ cnt,
                                                      uint* __restrict__ epack, int E, int N) {
  const int chunk = blockIdx.x & 7;
  const int group = blockIdx.x >> 3;
  const int ngroup = gridDim.x >> 3;
  const int c0 = (int)(((long)chunk * N) >> 3);
  const int c1 = (int)(((long)(chunk + 1) * N) >> 3);
  for (int e = group * 256 + threadIdx.x; e < E; e += ngroup * 256) {
    int d = dst[e];
    if (d < c0 || d >= c1) continue;
    int s = src[e];
    int slot = rowptr[d] + atomicAdd(&cnt[d], 1);
    float nm = dinv[s] * dinv[d];
    epack[slot] = (uint)s | ((uint)f2b(nm) << 16);
  }
}

// ---------------- fused weight prep (6 weights, bf16, transposed, padded) + x->bf16 pad ----------------
__global__ __launch_bounds__(256) void prep_all(const float* __restrict__ W1,
                                                const float* __restrict__ W2,
                                                const float* __restrict__ W3,
                                                const float* __restrict__ F1,
                                                const float* __restrict__ F2,
                                                const float* __restrict__ F3,
                                                const float* __restrict__ x,
                                                ushort* __restrict__ W1t, ushort* __restrict__ W2t,
                                                ushort* __restrict__ W3t, ushort* __restrict__ F1t,
                                                ushort* __restrict__ F2t, ushort* __restrict__ F3t,
                                                ushort* __restrict__ xb, int N) {
  int b = blockIdx.x;
  if (b < 384) {
    int wi = b >> 6;
    int i = (b & 63) * 256 + threadIdx.x;
    const float* W;
    ushort* Wt;
    int K, Kp, ncol;
    switch (wi) {
      case 0: W = W1; Wt = W1t; K = 50; Kp = 64; ncol = 128; break;
      case 1: W = W2; Wt = W2t; K = 128; Kp = 128; ncol = 128; break;
      case 2: W = W3; Wt = W3t; K = 128; Kp = 128; ncol = 128; break;
      case 3: W = F1; Wt = F1t; K = 128; Kp = 128; ncol = 128; break;
      case 4: W = F2; Wt = F2t; K = 128; Kp = 128; ncol = 128; break;
      default: W = F3; Wt = F3t; K = 128; Kp = 128; ncol = 121; break;
    }
    if (i >= 128 * Kp) return;
    int c = i / Kp, k = i - c * Kp;
    float w = (k < K && c < ncol) ? W[(size_t)k * ncol + c] : 0.f;
    Wt[(size_t)c * Kp + k] = f2b(w);
  } else {
    long i = (long)(b - 384) * 256 + threadIdx.x;
    if (i >= (long)N * 64) return;
    int n = (int)(i >> 6), k = (int)(i & 63);
    xb[i] = (k < 50) ? f2b(x[(size_t)n * 50 + k]) : (ushort)0;
  }
}

// ---------------- MFMA matmul: weights in VGPR, grid-stride over 32-row tiles ----------------
// Block = 4 waves; wave wq owns cols wq*32..wq*32+31 and preloads its B-frags ONCE.
template <int KSTEPS, bool BIAS, bool RELU>
__global__ __launch_bounds__(256) void mm_mfma(const ushort* __restrict__ X,
                                               const ushort* __restrict__ Wt,
                                               const float* __restrict__ bias,
                                               ushort* __restrict__ Yb, int N) {
  constexpr int K = KSTEPS * 32;
  const int lane = threadIdx.x & 63;
  const int wq = threadIdx.x >> 6;
  const int am = lane & 15;
  const int ag = lane >> 4;

  s16x8 wf[KSTEPS][2];
#pragma unroll
  for (int ks = 0; ks < KSTEPS; ++ks)
#pragma unroll
    for (int f = 0; f < 2; ++f)
      wf[ks][f] = *(const s16x8*)(Wt + (size_t)(wq * 32 + f * 16 + am) * K + ag * 8 + ks * 32);
  float bv[2] = {0.f, 0.f};
  if (BIAS) {
    bv[0] = bias[wq * 32 + am];
    bv[1] = bias[wq * 32 + 16 + am];
  }

  const int ntile = (N + 31) >> 5;
  for (int t = blockIdx.x; t < ntile; t += gridDim.x) {
    const long r0 = (long)t * 32;
    const bool v1 = (r0 + 16) < N;
    const ushort* x0 = X + (size_t)(r0 + am) * K + ag * 8;
    f32x4 acc[2][2] = {};
#pragma unroll
    for (int ks = 0; ks < KSTEPS; ++ks) {
      s16x8 a0 = *(const s16x8*)(x0 + ks * 32);
      s16x8 a1 = {};
      if (v1) a1 = *(const s16x8*)(x0 + (size_t)16 * K + ks * 32);
#pragma unroll
      for (int f = 0; f < 2; ++f) {
        acc[0][f] = __builtin_amdgcn_mfma_f32_16x16x32_bf16(a0, wf[ks][f], acc[0][f], 0, 0, 0);
        if (v1)
          acc[1][f] = __builtin_amdgcn_mfma_f32_16x16x32_bf16(a1, wf[ks][f], acc[1][f], 0, 0, 0);
      }
    }
#pragma unroll
    for (int m = 0; m < 2; ++m) {
      if (m == 1 && !v1) break;
#pragma unroll
      for (int f = 0; f < 2; ++f) {
        int col = wq * 32 + f * 16 + am;
#pragma unroll
        for (int r = 0; r < 4; ++r) {
          long row = r0 + m * 16 + ag * 4 + r;
          float v = acc[m][f][r] + bv[f];
          if (RELU) v = fmaxf(v, 0.f);
          Yb[row * 128 + col] = f2b(v);
        }
      }
    }
  }
}

// ---------------- fused FC head: all 3 weight sets in VGPR, grid-stride tiles ----------------
__global__ __launch_bounds__(256) void fc_fused(const ushort* __restrict__ X,
                                                const ushort* __restrict__ F1t,
                                                const ushort* __restrict__ F2t,
                                                const ushort* __restrict__ F3t,
                                                const float* __restrict__ b1,
                                                const float* __restrict__ b2,
                                                const float* __restrict__ b3,
                                                float* __restrict__ out, int N) {
  __shared__ ushort lds[32 * 128];  // 8 KB shared tile, XOR-swizzled
  const int lane = threadIdx.x & 63;
  const int wq = threadIdx.x >> 6;
  const int am = lane & 15;
  const int ag = lane >> 4;
  char* my = (char*)lds;

  // preload all three layers' B-fragments for this wave's 32 cols (96 VGPR)
  s16x8 wf1[4][2], wf2[4][2], wf3[4][2];
#pragma unroll
  for (int ks = 0; ks < 4; ++ks)
#pragma unroll
    for (int f = 0; f < 2; ++f) {
      size_t o = (size_t)(wq * 32 + f * 16 + am) * 128 + ag * 8 + ks * 32;
      wf1[ks][f] = *(const s16x8*)(F1t + o);
      wf2[ks][f] = *(const s16x8*)(F2t + o);
      wf3[ks][f] = *(const s16x8*)(F3t + o);
    }
  float b1v[2] = {b1[wq * 32 + am], b1[wq * 32 + 16 + am]};
  float b2v[2] = {b2[wq * 32 + am], b2[wq * 32 + 16 + am]};
  int c0 = wq * 32 + am, c1 = wq * 32 + 16 + am;
  float b3v[2] = {(c0 < 121) ? b3[c0] : 0.f, (c1 < 121) ? b3[c1] : 0.f};

  // stage this wave's 32x32 quarter (D-layout) into the shared tile, bf16+swizzle
  auto stage = [&](f32x4 acc[2][2], const float* bv) {
#pragma unroll
    for (int m = 0; m < 2; ++m)
#pragma unroll
      for (int f = 0; f < 2; ++f) {
        int col = wq * 32 + f * 16 + am;
#pragma unroll
        for (int r = 0; r < 4; ++r) {
          int row = m * 16 + ag * 4 + r;
          uint byte = (uint)(row * 256 + col * 2) ^ ((uint)(row & 7) << 4);
          *(ushort*)(my + byte) = f2b(fmaxf(acc[m][f][r] + bv[f], 0.f));
        }
      }
  };
  auto loadA = [&](int m, int ks) -> s16x8 {
    int row = m * 16 + am;
    uint byte = (uint)(row * 256 + ks * 64 + ag * 16) ^ ((uint)(row & 7) << 4);
    return *(const s16x8*)(my + byte);
  };

  const int ntile = (N + 31) >> 5;
  for (int t = blockIdx.x; t < ntile; t += gridDim.x) {
    const long r0 = (long)t * 32;
    const bool v1 = (r0 + 16) < N;
    const ushort* x0 = X + (size_t)(r0 + am) * 128 + ag * 8;

    // fc1 (A from global)
    f32x4 a1c[2][2] = {};
#pragma unroll
    for (int ks = 0; ks < 4; ++ks) {
      s16x8 a0 = *(const s16x8*)(x0 + ks * 32);
      s16x8 a1 = v1 ? *(const s16x8*)(x0 + (size_t)16 * 128 + ks * 32) : s16x8{};
#pragma unroll
      for (int f = 0; f < 2; ++f) {
        a1c[0][f] = __builtin_amdgcn_mfma_f32_16x16x32_bf16(a0, wf1[ks][f], a1c[0][f], 0, 0, 0);
        a1c[1][f] = __builtin_amdgcn_mfma_f32_16x16x32_bf16(a1, wf1[ks][f], a1c[1][f], 0, 0, 0);
      }
    }
    stage(a1c, b1v);
    __syncthreads();
    // fc2 (A from LDS)
    f32x4 a2c[2][2] = {};
#pragma unroll
    for (int ks = 0; ks < 4; ++ks) {
      s16x8 a0 = loadA(0, ks);
      s16x8 a1 = loadA(1, ks);
#pragma unroll
      for (int f = 0; f < 2; ++f) {
        a2c[0][f] = __builtin_amdgcn_mfma_f32_16x16x32_bf16(a0, wf2[ks][f], a2c[0][f], 0, 0, 0);
        a2c[1][f] = __builtin_amdgcn_mfma_f32_16x16x32_bf16(a1, wf2[ks][f], a2c[1][f], 0, 0, 0);
      }
    }
    __syncthreads();  // all fc2 LDS reads done before overwrite
    stage(a2c, b2v);
    __syncthreads();
    // fc3 (A from LDS)
    f32x4 a3c[2][2] = {};
#pragma unroll
    for (int ks = 0; ks < 4; ++ks) {
      s16x8 a0 = loadA(0, ks);
      s16x8 a1 = loadA(1, ks);
#pragma unroll
      for (int f = 0; f < 2; ++f) {
        a3c[0][f] = __builtin_amdgcn_mfma_f32_16x16x32_bf16(a0, wf3[ks][f], a3c[0][f], 0, 0, 0);
        a3c[1][f] = __builtin_amdgcn_mfma_f32_16x16x32_bf16(a1, wf3[ks][f], a3c[1][f], 0, 0, 0);
      }
    }
    // final store: f32, 121 cols
#pragma unroll
    for (int m = 0; m < 2; ++m) {
      if (m == 1 && !v1) break;
#pragma unroll
      for (int f = 0; f < 2; ++f) {
        int col = wq * 32 + f * 16 + am;
        if (col >= 121) continue;
#pragma unroll
        for (int r = 0; r < 4; ++r) {
          long row = r0 + m * 16 + ag * 4 + r;
          out[row * 121 + col] = a3c[m][f][r] + b3v[f];
        }
      }
    }
    __syncthreads();  // protect LDS before next tile's stage
  }
}

// ---------------- CSR aggregation, 8-deep pipelined gather ----------------
template <int RW, bool ACT>
__global__ __launch_bounds__(256) void agg_kernel(const ushort* __restrict__ Hm,
                                                  const int* __restrict__ rowptr,
                                                  const uint* __restrict__ epack,
                                                  const float* __restrict__ dinv,
                                                  const float* __restrict__ b,
                                                  ushort* __restrict__ Y, int N) {
  int wave = threadIdx.x >> 6;
  int lane = threadIdx.x & 63;
  int n = blockIdx.x * 4 + wave;
  if (n >= N) return;
  int beg = rowptr[n], end = rowptr[n + 1];
  float dn = dinv[n];
  float d2 = dn * dn;
  int i = beg;

  if constexpr (RW == 128) {
    int f = lane * 2;
    float ax = 0.f, ay = 0.f;
    while (i + 8 <= end) {
      uint rec[8];
#pragma unroll
      for (int j = 0; j < 8; ++j) rec[j] = epack[i + j];
      uint v[8];
#pragma unroll
      for (int j = 0; j < 8; ++j)
        v[j] = *(const uint*)&Hm[(size_t)(rec[j] & 0xffffu) * 128 + f];
#pragma unroll
      for (int j = 0; j < 8; ++j) {
        float nm = __uint_as_float(rec[j] & 0xffff0000u);
        ax += b2f(v[j] & 0xffffu) * nm;
        ay += b2f(v[j] >> 16) * nm;
      }
      i += 8;
    }
    if (i + 4 <= end) {
      uint rec[4];
#pragma unroll
      for (int j = 0; j < 4; ++j) rec[j] = epack[i + j];
      uint v[4];
#pragma unroll
      for (int j = 0; j < 4; ++j)
        v[j] = *(const uint*)&Hm[(size_t)(rec[j] & 0xffffu) * 128 + f];
#pragma unroll
      for (int j = 0; j < 4; ++j) {
        float nm = __uint_as_float(rec[j] & 0xffff0000u);
        ax += b2f(v[j] & 0xffffu) * nm;
        ay += b2f(v[j] >> 16) * nm;
      }
      i += 4;
    }
    for (; i < end; ++i) {
      uint rec = epack[i];
      float nm = __uint_as_float(rec & 0xffff0000u);
      uint v = *(const uint*)&Hm[(size_t)(rec & 0xffffu) * 128 + f];
      ax += b2f(v & 0xffffu) * nm;
      ay += b2f(v >> 16) * nm;
    }
    uint sv = *(const uint*)&Hm[(size_t)n * 128 + f];
    ax += b2f(sv & 0xffffu) * d2;
    ay += b2f(sv >> 16) * d2;
    if (ACT) {
      ax = fmaxf(ax + b[f], 0.f);
      ay = fmaxf(ay + b[f + 1], 0.f);
    }
    uint out = (uint)f2b(ax) | ((uint)f2b(ay) << 16);
    *(uint*)&Y[(size_t)n * 128 + f] = out;
  } else {
    int f = lane;
    float ax = 0.f;
    while (i + 8 <= end) {
      uint rec[8];
#pragma unroll
      for (int j = 0; j < 8; ++j) rec[j] = epack[i + j];
      ushort v[8];
#pragma unroll
      for (int j = 0; j < 8; ++j)
        v[j] = Hm[(size_t)(rec[j] & 0xffffu) * 64 + f];
#pragma unroll
      for (int j = 0; j < 8; ++j)
        ax += b2f(v[j]) * __uint_as_float(rec[j] & 0xffff0000u);
      i += 8;
    }
    if (i + 4 <= end) {
      uint rec[4];
#pragma unroll
      for (int j = 0; j < 4; ++j) rec[j] = epack[i + j];
      ushort v[4];
#pragma unroll
      for (int j = 0; j < 4; ++j)
        v[j] = Hm[(size_t)(rec[j] & 0xffffu) * 64 + f];
#pragma unroll
      for (int j = 0; j < 4; ++j)
        ax += b2f(v[j]) * __uint_as_float(rec[j] & 0xffff0000u);
      i += 4;
    }
    for (; i < end; ++i) {
      uint rec = epack[i];
      ax += b2f(Hm[(size_t)(rec & 0xffffu) * 64 + f]) * __uint_as_float(rec & 0xffff0000u);
    }
    ax += b2f(Hm[(size_t)n * 64 + f]) * d2;
    if (ACT) ax = fmaxf(ax + b[f], 0.f);
    Y[(size_t)n * 64 + f] = f2b(ax);
  }
}

// ---------------- launch ----------------
extern "C" void kernel_launch(void* const* d_in, const int* in_sizes, int n_in,
                              void* d_out, int out_size, void* d_ws, size_t ws_size,
                              hipStream_t stream) {
  const float* x    = (const float*)d_in[0];
  const void*  ei   = d_in[1];
  const float* W1   = (const float*)d_in[3];
  const float* b1   = (const float*)d_in[4];
  const float* W2   = (const float*)d_in[5];
  const float* b2   = (const float*)d_in[6];
  const float* W3   = (const float*)d_in[7];
  const float* b3   = (const float*)d_in[8];
  const float* fcW1 = (const float*)d_in[9];
  const float* fcb1 = (const float*)d_in[10];
  const float* fcW2 = (const float*)d_in[11];
  const float* fcb2 = (const float*)d_in[12];
  const float* fcW3 = (const float*)d_in[13];
  const float* fcb3 = (const float*)d_in[14];

  const int FIN = 50;
  const int N = in_sizes[0] / FIN;
  const int E = in_sizes[1] / 2;
  const int NCHUNK = (N + SCAN_CHUNK - 1) / SCAN_CHUNK;

  size_t off = 0;
  auto carve = [&](size_t bytes) {
    void* p = (char*)d_ws + off;
    off += (bytes + 255) & ~(size_t)255;
    return p;
  };
  int*    src32    = (int*)carve((size_t)E * 4);
  int*    dst32    = (int*)carve((size_t)E * 4);
  uint*   epack    = (uint*)carve((size_t)E * 4);
  int*    degi     = (int*)carve((size_t)N * 4);  // later reused as cnt for scatter
  int*    rowptr   = (int*)carve((size_t)(N + 1) * 4);
  float*  dinv     = (float*)carve((size_t)N * 4);
  int*    partials = (int*)carve((size_t)NCHUNK * 4);
  ushort* W1t      = (ushort*)carve((size_t)128 * 64 * 2);
  ushort* W2t      = (ushort*)carve((size_t)128 * 128 * 2);
  ushort* W3t      = (ushort*)carve((size_t)128 * 128 * 2);
  ushort* F1t      = (ushort*)carve((size_t)128 * 128 * 2);
  ushort* F2t      = (ushort*)carve((size_t)128 * 128 * 2);
  ushort* F3t      = (ushort*)carve((size_t)128 * 128 * 2);
  ushort* xb       = (ushort*)carve((size_t)N * 64 * 2);
  ushort* aggX     = (ushort*)carve((size_t)N * 64 * 2);
  ushort* bufA     = (ushort*)carve((size_t)N * 128 * 2);
  ushort* bufB     = (ushort*)carve((size_t)N * 128 * 2);

  const int gE = (E + 255) / 256;
  const int gMM = 1024;  // grid-stride over (N+31)/32 row tiles
  const int gAGG = (N + 3) / 4;
  const int gPREP = 384 + (int)(((long)N * 64 + 255) / 256);

  // --- graph preprocessing ---
  hipMemsetAsync(degi, 0, (size_t)N * 4, stream);
  convert_hist_kernel<<<gE, 256, 0, stream>>>(ei, src32, dst32, degi, E);
  chunk_reduce_kernel<<<NCHUNK, 256, 0, stream>>>(degi, partials, N);
  chunk_scan_kernel<<<NCHUNK, 256, 0, stream>>>(degi, partials, NCHUNK, rowptr, dinv, N, E);
  scatter_kernel<<<1024, 256, 0, stream>>>(src32, dst32, rowptr, dinv, degi, epack, E, N);
  prep_all<<<gPREP, 256, 0, stream>>>(W1, W2, W3, fcW1, fcW2, fcW3, x,
                                      W1t, W2t, W3t, F1t, F2t, F3t, xb, N);

  // --- conv layer 1 (aggregate 64-wide input, then mm with fused bias+relu) ---
  agg_kernel<64, false><<<gAGG, 256, 0, stream>>>(xb, rowptr, epack, dinv, nullptr, aggX, N);
  mm_mfma<2, true, true><<<gMM, 256, 0, stream>>>(aggX, W1t, b1, bufA, N);
  // --- conv layer 2 ---
  mm_mfma<4, false, false><<<gMM, 256, 0, stream>>>(bufA, W2t, nullptr, bufB, N);
  agg_kernel<128, true><<<gAGG, 256, 0, stream>>>(bufB, rowptr, epack, dinv, b2, bufA, N);
  // --- conv layer 3 ---
  mm_mfma<4, false, false><<<gMM, 256, 0, stream>>>(bufA, W3t, nullptr, bufB, N);
  agg_kernel<128, true><<<gAGG, 256, 0, stream>>>(bufB, rowptr, epack, dinv, b3, bufA, N);
  // --- fused FC head ---
  fc_fused<<<gMM, 256, 0, stream>>>(bufA, F1t, F2t, F3t, fcb1, fcb2, fcb3,
                                    (float*)d_out, N);
}